// Round 19
// baseline (253.883 us; speedup 1.0000x reference)
//
#include <hip/hip_runtime.h>
#include <hip/hip_bf16.h>
#include <math.h>

typedef unsigned short u16;
typedef __bf16 bf16x8 __attribute__((ext_vector_type(8)));
typedef float f32x4 __attribute__((ext_vector_type(4)));
typedef u16 u16x8 __attribute__((ext_vector_type(8)));

#define MFMA16(a, b, c) __builtin_amdgcn_mfma_f32_16x16x32_bf16((a), (b), (c), 0, 0, 0)

__device__ __forceinline__ u16 f2bf(float f) {
  unsigned u = __float_as_uint(f);
  u += 0x7fffu + ((u >> 16) & 1u);
  return (u16)(u >> 16);
}
__device__ __forceinline__ float bf2f(u16 u) {
  return __uint_as_float((unsigned)u << 16);
}

__device__ __forceinline__ void glds16(const u16* g, u16* l) {
  __builtin_amdgcn_global_load_lds((__attribute__((address_space(1))) const void*)g,
                                   (__attribute__((address_space(3))) void*)l, 16, 0, 0);
}

// ---------------- LayerNorm: fp32 [rows][1024] -> bf16 [rows][1024] ----------------
__global__ __launch_bounds__(256) void ln_k(const float* __restrict__ X,
                                            const float* __restrict__ G,
                                            const float* __restrict__ Bv,
                                            u16* __restrict__ out) {
  const int row = blockIdx.x;
  const int t = threadIdx.x;
  const float4 v = reinterpret_cast<const float4*>(X + (size_t)row * 1024)[t];
  float s = v.x + v.y + v.z + v.w;
  float q = v.x * v.x + v.y * v.y + v.z * v.z + v.w * v.w;
  for (int off = 32; off > 0; off >>= 1) {
    s += __shfl_down(s, off);
    q += __shfl_down(q, off);
  }
  __shared__ float ss[4], qs[4];
  const int w = t >> 6, l = t & 63;
  if (l == 0) { ss[w] = s; qs[w] = q; }
  __syncthreads();
  s = ss[0] + ss[1] + ss[2] + ss[3];
  q = qs[0] + qs[1] + qs[2] + qs[3];
  const float mu = s * (1.0f / 1024.0f);
  const float rs = rsqrtf(q * (1.0f / 1024.0f) - mu * mu + 1e-5f);
  const float4 gv = reinterpret_cast<const float4*>(G)[t];
  const float4 bv = reinterpret_cast<const float4*>(Bv)[t];
  union { u16 u[4]; unsigned long long ll; } pk;
  pk.u[0] = f2bf((v.x - mu) * rs * gv.x + bv.x);
  pk.u[1] = f2bf((v.y - mu) * rs * gv.y + bv.y);
  pk.u[2] = f2bf((v.z - mu) * rs * gv.z + bv.z);
  pk.u[3] = f2bf((v.w - mu) * rs * gv.w + bv.w);
  *reinterpret_cast<unsigned long long*>(out + (size_t)row * 1024 + t * 4) = pk.ll;
}

// ---- merged weight convert+transpose: 12 z-slices of 32x32-block transposes ----
__global__ __launch_bounds__(256) void wconv12_k(const float* __restrict__ Wq,
                                                 const float* __restrict__ Wk,
                                                 const float* __restrict__ Wv,
                                                 const float* __restrict__ Wo,
                                                 const float* __restrict__ W1,
                                                 const float* __restrict__ W2,
                                                 u16* __restrict__ Wqkvt,
                                                 u16* __restrict__ Wot,
                                                 u16* __restrict__ W1t,
                                                 u16* __restrict__ W2t) {
  __shared__ u16 tile[32][33];
  const int z = blockIdx.z;
  const float* W;
  u16* Wt;
  int K, N, n0, k0;
  if (z < 4) {
    W = (z == 0) ? Wq : (z == 1) ? Wk : (z == 2) ? Wv : Wo;
    Wt = (z == 3) ? Wot : (Wqkvt + (size_t)z * 1024 * 1024);
    K = 1024; N = 1024;
    n0 = blockIdx.x * 32; k0 = blockIdx.y * 32;
  } else if (z < 8) {
    W = W1; Wt = W1t; K = 1024; N = 4096;
    n0 = blockIdx.x * 32 + (z - 4) * 1024; k0 = blockIdx.y * 32;
  } else {
    W = W2; Wt = W2t; K = 4096; N = 1024;
    n0 = blockIdx.x * 32; k0 = blockIdx.y * 32 + (z - 8) * 1024;
  }
  const int x = threadIdx.x, y = threadIdx.y;
#pragma unroll
  for (int i = 0; i < 4; ++i)
    tile[y + i * 8][x] = f2bf(W[(size_t)(k0 + y + i * 8) * N + n0 + x]);
  __syncthreads();
#pragma unroll
  for (int i = 0; i < 4; ++i)
    Wt[(size_t)(n0 + y + i * 8) * K + k0 + x] = tile[x][y + i * 8];
}

// ------- GEMM 128x128, BK=64 single-buffer, 4 waves — ALL GEMMs -------------------
// 32 KB LDS (<=5 blocks/CU); stage inst i covers rows i*32+(t>>3), chunk
// (t&7)^(row&7) involution; 2 k-steps x 16 MFMA per phase.
// EPI 0: bf16 store (kz partial offset); 1: bias+exact GELU bf16; 2: fp32 res+acc.
// VT (QKV only, N=3072): bx>=16 writes V transposed into Vtp[32][64][2048].
template <int EPI, bool VT>
__global__ __launch_bounds__(256) void gemm_bt64(const u16* __restrict__ A,
                                                 const u16* __restrict__ Bt,
                                                 u16* __restrict__ Cb, float* Cf,
                                                 u16* __restrict__ Vtp,
                                                 const float* __restrict__ bias,
                                                 const float* res, int M, int N,
                                                 int K, int kzSplit) {
  __shared__ __align__(16) u16 As[8192];   // [128][64]
  __shared__ __align__(16) u16 Bs[8192];
  const int t = threadIdx.x;
  const int l = t & 63, w = t >> 6;
  const int nbx = N >> 7;
  const int id = blockIdx.x;
  int tiles, tid, kz;
  if (kzSplit) {  // grid = 2 * 256; kz = id >> 8
    kz = id >> 8;
    tid = id & 255;
    tiles = 256;
  } else {
    kz = 0;
    tid = id;
    tiles = (int)gridDim.x;
  }
  const int qd = tiles >> 3;
  const int swz = (tid & 7) * qd + (tid >> 3);  // XCD swizzle (tiles % 8 == 0)
  const int by = swz / nbx, bx = swz - by * nbx;
  const int Keff = kzSplit ? (K >> 1) : K;
  const int koff = kz * Keff;

  const int scol = ((t & 7) ^ ((t >> 3) & 7)) * 8;
  const u16* gA = A + (size_t)(by * 128 + (t >> 3)) * K + koff + scol;
  const u16* gB = Bt + (size_t)(bx * 128 + (t >> 3)) * K + koff + scol;
  const size_t r32K = (size_t)32 * K;
  const int dst = t * 8;

  const int wr = w >> 1, wc = w & 1;
  const int arow = (wr * 64 + (l & 15)) * 64;
  const int brow = (wc * 64 + (l & 15)) * 64;
  const int ck0 = ((l >> 4) ^ (l & 7)) * 8;
  const int ck1 = ((4 + (l >> 4)) ^ (l & 7)) * 8;

  const f32x4 fz = {0.f, 0.f, 0.f, 0.f};
  f32x4 acc[4][4];
#pragma unroll
  for (int i = 0; i < 4; ++i)
#pragma unroll
    for (int j = 0; j < 4; ++j) acc[i][j] = fz;

  const int nk = Keff >> 6;
  for (int kk = 0; kk < nk; ++kk) {
    __syncthreads();
#pragma unroll
    for (int i = 0; i < 4; ++i) {
      glds16(gA + i * r32K, As + i * 2048 + dst);
      glds16(gB + i * r32K, Bs + i * 2048 + dst);
    }
    gA += 64;
    gB += 64;
    __syncthreads();
#pragma unroll
    for (int ks = 0; ks < 2; ++ks) {
      const int ck = ks ? ck1 : ck0;
      bf16x8 af[4], bv[4];
#pragma unroll
      for (int i = 0; i < 4; ++i)
        af[i] = *reinterpret_cast<const bf16x8*>(&As[arow + i * 1024 + ck]);
#pragma unroll
      for (int j = 0; j < 4; ++j)
        bv[j] = *reinterpret_cast<const bf16x8*>(&Bs[brow + j * 1024 + ck]);
      __builtin_amdgcn_s_setprio(1);
#pragma unroll
      for (int i = 0; i < 4; ++i)
#pragma unroll
        for (int j = 0; j < 4; ++j) acc[i][j] = MFMA16(af[i], bv[j], acc[i][j]);
      __builtin_amdgcn_s_setprio(0);
    }
  }

  const int r0 = by * 128 + wr * 64 + ((l >> 4) << 2);
  const int c0 = bx * 128 + wc * 64 + (l & 15);
  if (VT && bx >= 16) {  // V block: write transposed into Vt[bh][dk][t]
    const int hh = (bx - 16) * 2 + wc;
    const int b = by >> 4;
    const size_t hb = ((size_t)b * 16 + hh) * 64;
#pragma unroll
    for (int mi = 0; mi < 4; ++mi) {
      const int t0 = ((by & 15) * 128) + wr * 64 + ((l >> 4) << 2) + mi * 16;
#pragma unroll
      for (int ni = 0; ni < 4; ++ni) {
        const int dk = ni * 16 + (l & 15);
        union { u16 u[4]; unsigned long long ll; } pk;
#pragma unroll
        for (int r = 0; r < 4; ++r) pk.u[r] = f2bf(acc[mi][ni][r]);
        *reinterpret_cast<unsigned long long*>(&Vtp[(hb + dk) * 2048 + t0]) = pk.ll;
      }
    }
  } else if (EPI == 0) {
    u16* Cp = Cb + (size_t)kz * M * N;
#pragma unroll
    for (int mi = 0; mi < 4; ++mi)
#pragma unroll
      for (int ni = 0; ni < 4; ++ni) {
        const size_t base = (size_t)(r0 + mi * 16) * N + (c0 + ni * 16);
#pragma unroll
        for (int r = 0; r < 4; ++r) Cp[base + (size_t)r * N] = f2bf(acc[mi][ni][r]);
      }
  } else if (EPI == 1) {
#pragma unroll
    for (int mi = 0; mi < 4; ++mi)
#pragma unroll
      for (int ni = 0; ni < 4; ++ni) {
        const int col = c0 + ni * 16;
        const float bb = bias[col];
        const size_t base = (size_t)(r0 + mi * 16) * N + col;
#pragma unroll
        for (int r = 0; r < 4; ++r) {
          const float x = acc[mi][ni][r] + bb;
          const float gl = 0.5f * x * (1.0f + erff(x * 0.70710678118654752f));
          Cb[base + (size_t)r * N] = f2bf(gl);
        }
      }
  } else {
#pragma unroll
    for (int mi = 0; mi < 4; ++mi)
#pragma unroll
      for (int ni = 0; ni < 4; ++ni) {
        const int col = c0 + ni * 16;
        const float bb = bias ? bias[col] : 0.0f;
        const size_t base = (size_t)(r0 + mi * 16) * N + col;
#pragma unroll
        for (int r = 0; r < 4; ++r) {
          const size_t idx = base + (size_t)r * N;
          Cf[idx] = res[idx] + acc[mi][ni][r] + bb;
        }
      }
  }
}

// ---------------- reduce: out += P0 + P1 + bias  (4096x1024 f32) ----------------
__global__ __launch_bounds__(256) void reduce_k(float* __restrict__ out,
                                                const u16* __restrict__ P0,
                                                const u16* __restrict__ P1,
                                                const float* __restrict__ bias) {
  const int q0 = blockIdx.x * 256 + threadIdx.x;
#pragma unroll
  for (int it = 0; it < 2; ++it) {
    const size_t q = ((size_t)q0 + (size_t)it * 524288) * 4;
    float4 o = *reinterpret_cast<float4*>(&out[q]);
    const ushort4 a = *reinterpret_cast<const ushort4*>(&P0[q]);
    const ushort4 b = *reinterpret_cast<const ushort4*>(&P1[q]);
    const float4 bb = *reinterpret_cast<const float4*>(&bias[q & 1023]);
    o.x += bf2f(a.x) + bf2f(b.x) + bb.x;
    o.y += bf2f(a.y) + bf2f(b.y) + bb.y;
    o.z += bf2f(a.z) + bf2f(b.z) + bb.z;
    o.w += bf2f(a.w) + bf2f(b.w) + bb.w;
    *reinterpret_cast<float4*>(&out[q]) = o;
  }
}

// ---------------- causal flash attention (LDS-staged K/V, 8 waves, 128-row qblk) ----
__global__ __launch_bounds__(512) void attn_k(const u16* __restrict__ QKV,
                                              const u16* __restrict__ Vt,
                                              u16* __restrict__ O) {
  __shared__ __align__(16) u16 Kbuf[2][4096];
  __shared__ __align__(16) u16 Vbuf[2][4096];
  __shared__ __align__(16) u16 Plds[8][16][68];
  const int t = threadIdx.x;
  const int l = t & 63, w = t >> 6;
  const int g = l >> 4, c = l & 15;
  const int pj = blockIdx.x, bh = blockIdx.y;
  const int b = bh >> 4, h = bh & 15;
  const u16* Kp = QKV + (size_t)b * 2048 * 3072 + 1024 + h * 64;
  const u16* Vp = Vt + (size_t)bh * 64 * 2048;
  const f32x4 fz = {0.f, 0.f, 0.f, 0.f};
  const int srow = t >> 3;
  const int scol = ((t & 7) ^ (srow & 7)) * 8;
  u16* kdst0 = &Kbuf[0][w * 512];
  u16* kdst1 = &Kbuf[1][w * 512];
  u16* vdst0 = &Vbuf[0][w * 512];
  u16* vdst1 = &Vbuf[1][w * 512];
  const int ca = (g ^ (c & 7)) * 8;
  const int cb = ((g + 4) ^ (c & 7)) * 8;

#pragma unroll 1
  for (int hf = 0; hf < 2; ++hf) {
    const int qblk = hf ? (15 - pj) : pj;
    const int nkt = 2 * qblk + 2;
    const int qrow0 = qblk * 128 + w * 16;
    const size_t qoff = (size_t)(b * 2048 + qrow0 + c) * 3072 + h * 64 + g * 8;
    const bf16x8 qf0 = *reinterpret_cast<const bf16x8*>(&QKV[qoff]);
    const bf16x8 qf1 = *reinterpret_cast<const bf16x8*>(&QKV[qoff + 32]);
    f32x4 o[4];
    float m[4], lsl[4];
#pragma unroll
    for (int f = 0; f < 4; ++f) o[f] = fz;
#pragma unroll
    for (int r = 0; r < 4; ++r) {
      m[r] = -__builtin_inff();
      lsl[r] = 0.f;
    }
    glds16(Kp + (size_t)srow * 3072 + scol, kdst0);
    glds16(Vp + (size_t)srow * 2048 + scol, vdst0);
    __syncthreads();
    int cur = 0;

#pragma unroll 1
    for (int kt = 0; kt < nkt; ++kt) {
      const int key0 = kt * 64;
      if (kt + 1 < nkt) {
        const int kn = key0 + 64;
        glds16(Kp + (size_t)(kn + srow) * 3072 + scol, cur ? kdst0 : kdst1);
        glds16(Vp + (size_t)srow * 2048 + kn + scol, cur ? vdst0 : vdst1);
      }
      if (key0 <= qrow0 + 15) {
        const u16* Kc = Kbuf[cur];
        const u16* Vc = Vbuf[cur];
        f32x4 s4[4];
        __builtin_amdgcn_s_setprio(1);
#pragma unroll
        for (int kq = 0; kq < 4; ++kq) {
          const int rb = (c + 16 * kq) * 64;
          const bf16x8 k0 = *reinterpret_cast<const bf16x8*>(&Kc[rb + ca]);
          const bf16x8 k1 = *reinterpret_cast<const bf16x8*>(&Kc[rb + cb]);
          s4[kq] = MFMA16(qf0, k0, fz);
          s4[kq] = MFMA16(qf1, k1, s4[kq]);
        }
        __builtin_amdgcn_s_setprio(0);
        bf16x8 vf[8];
#pragma unroll
        for (int f = 0; f < 4; ++f) {
          const int rb = (c + 16 * f) * 64;
          vf[f * 2] = *reinterpret_cast<const bf16x8*>(&Vc[rb + ca]);
          vf[f * 2 + 1] = *reinterpret_cast<const bf16x8*>(&Vc[rb + cb]);
        }
        const bool maskT = (kt >= nkt - 2);
        float xs[4][4];
        float mx4 = -__builtin_inff();
#pragma unroll
        for (int r = 0; r < 4; ++r) {
          const int qg = qrow0 + g * 4 + r;
          xs[r][0] = s4[0][r] * 0.125f;
          xs[r][1] = s4[1][r] * 0.125f;
          xs[r][2] = s4[2][r] * 0.125f;
          xs[r][3] = s4[3][r] * 0.125f;
          if (maskT) {
            if (key0 + c > qg) xs[r][0] = -__builtin_inff();
            if (key0 + 16 + c > qg) xs[r][1] = -__builtin_inff();
            if (key0 + 32 + c > qg) xs[r][2] = -__builtin_inff();
            if (key0 + 48 + c > qg) xs[r][3] = -__builtin_inff();
          }
          const float a0 = fmaxf(xs[r][0], xs[r][1]);
          const float a1 = fmaxf(xs[r][2], xs[r][3]);
          mx4 = fmaxf(mx4, fmaxf(a0, a1) - m[r]);
        }
        if (!__all(mx4 <= 8.0f)) {
#pragma unroll
          for (int r = 0; r < 4; ++r) {
            float tm = fmaxf(fmaxf(xs[r][0], xs[r][1]), fmaxf(xs[r][2], xs[r][3]));
            tm = fmaxf(tm, __shfl_xor(tm, 1, 16));
            tm = fmaxf(tm, __shfl_xor(tm, 2, 16));
            tm = fmaxf(tm, __shfl_xor(tm, 4, 16));
            tm = fmaxf(tm, __shfl_xor(tm, 8, 16));
            const float mn = fmaxf(m[r], tm);
            const float scl = __expf(m[r] - mn);
            lsl[r] *= scl;
            m[r] = mn;
            o[0][r] *= scl;
            o[1][r] *= scl;
            o[2][r] *= scl;
            o[3][r] *= scl;
          }
        }
#pragma unroll
        for (int r = 0; r < 4; ++r) {
          const float p0 = __expf(xs[r][0] - m[r]), p1 = __expf(xs[r][1] - m[r]);
          const float p2 = __expf(xs[r][2] - m[r]), p3 = __expf(xs[r][3] - m[r]);
          lsl[r] += (p0 + p1) + (p2 + p3);
          const int pr = g * 4 + r;
          Plds[w][pr][c] = f2bf(p0);
          Plds[w][pr][c + 16] = f2bf(p1);
          Plds[w][pr][c + 32] = f2bf(p2);
          Plds[w][pr][c + 48] = f2bf(p3);
        }
        asm volatile("" ::: "memory");
        const bf16x8 pa0 = *reinterpret_cast<const bf16x8*>(&Plds[w][c][g * 8]);
        const bf16x8 pa1 = *reinterpret_cast<const bf16x8*>(&Plds[w][c][32 + g * 8]);
        __builtin_amdgcn_s_setprio(1);
#pragma unroll
        for (int f = 0; f < 4; ++f) {
          o[f] = MFMA16(pa0, vf[f * 2], o[f]);
          o[f] = MFMA16(pa1, vf[f * 2 + 1], o[f]);
        }
        __builtin_amdgcn_s_setprio(0);
      }
      __syncthreads();
      cur ^= 1;
    }

    u16* op = O + (size_t)(b * 2048 + qrow0 + g * 4) * 1024 + h * 64 + c;
#pragma unroll
    for (int r = 0; r < 4; ++r) {
      float ls = lsl[r];
      ls += __shfl_xor(ls, 1, 16);
      ls += __shfl_xor(ls, 2, 16);
      ls += __shfl_xor(ls, 4, 16);
      ls += __shfl_xor(ls, 8, 16);
      const float inv = 1.0f / ls;
#pragma unroll
      for (int f = 0; f < 4; ++f) op[(size_t)r * 1024 + f * 16] = f2bf(o[f][r] * inv);
    }
  }
}

// ---------------- launcher ----------------
extern "C" void kernel_launch(void* const* d_in, const int* in_sizes, int n_in,
                              void* d_out, int out_size, void* d_ws, size_t ws_size,
                              hipStream_t stream) {
  const float* H   = (const float*)d_in[0];
  const float* Wq  = (const float*)d_in[1];
  const float* Wk  = (const float*)d_in[2];
  const float* Wv  = (const float*)d_in[3];
  const float* Wo  = (const float*)d_in[4];
  const float* g1  = (const float*)d_in[5];
  const float* be1 = (const float*)d_in[6];
  const float* g2  = (const float*)d_in[7];
  const float* be2 = (const float*)d_in[8];
  const float* W1  = (const float*)d_in[9];
  const float* bb1 = (const float*)d_in[10];
  const float* W2  = (const float*)d_in[11];
  const float* bb2 = (const float*)d_in[12];
  float* out = (float*)d_out;

  if (ws_size < (size_t)67108864) return;  // need 64 MiB
  char* ws = (char*)d_ws;
  u16* Wqkvt = (u16*)(ws + 0);
  u16* Xattn = (u16*)(ws + 6291456);
  u16* QKV   = (u16*)(ws + 14680064);
  u16* Vt    = (u16*)(ws + 39845888);
  u16* Wot   = (u16*)(ws + 48234496);
  u16* W1t   = (u16*)(ws + 50331648);
  u16* W2t   = (u16*)(ws + 58720256);
  u16* Hmlp  = (u16*)(ws + 0);
  u16* Xln2  = Vt;
  u16* Pp    = (u16*)(ws + 39845888);

  wconv12_k<<<dim3(32, 32, 12), dim3(32, 8), 0, stream>>>(Wq, Wk, Wv, Wo, W1, W2,
                                                          Wqkvt, Wot, W1t, W2t);
  ln_k<<<4096, 256, 0, stream>>>(H, g1, be1, Xattn);
  gemm_bt64<0, true><<<768, 256, 0, stream>>>(Xattn, Wqkvt, QKV, nullptr, Vt,
                                              nullptr, nullptr, 4096, 3072, 1024, 0);
  attn_k<<<dim3(8, 32), 512, 0, stream>>>(QKV, Vt, Xattn);
  gemm_bt64<2, false><<<256, 256, 0, stream>>>(Xattn, Wot, nullptr, out, nullptr,
                                               nullptr, H, 4096, 1024, 1024, 0);
  ln_k<<<4096, 256, 0, stream>>>(out, g2, be2, Xln2);
  gemm_bt64<1, false><<<1024, 256, 0, stream>>>(Xln2, W1t, Hmlp, nullptr, nullptr,
                                                bb1, nullptr, 4096, 4096, 1024, 0);
  gemm_bt64<0, false><<<512, 256, 0, stream>>>(Hmlp, W2t, Pp, nullptr, nullptr,
                                               nullptr, nullptr, 4096, 1024, 4096, 1);
  reduce_k<<<2048, 256, 0, stream>>>(out, Pp, Pp + (size_t)4096 * 1024, bb2);
}

// Round 20
// 235.882 us; speedup vs baseline: 1.0763x; 1.0763x over previous
//
#include <hip/hip_runtime.h>
#include <hip/hip_bf16.h>
#include <math.h>

typedef unsigned short u16;
typedef __bf16 bf16x8 __attribute__((ext_vector_type(8)));
typedef float f32x4 __attribute__((ext_vector_type(4)));
typedef u16 u16x8 __attribute__((ext_vector_type(8)));

#define MFMA16(a, b, c) __builtin_amdgcn_mfma_f32_16x16x32_bf16((a), (b), (c), 0, 0, 0)

__device__ __forceinline__ u16 f2bf(float f) {
  unsigned u = __float_as_uint(f);
  u += 0x7fffu + ((u >> 16) & 1u);
  return (u16)(u >> 16);
}
__device__ __forceinline__ float bf2f(u16 u) {
  return __uint_as_float((unsigned)u << 16);
}

__device__ __forceinline__ void glds16(const u16* g, u16* l) {
  __builtin_amdgcn_global_load_lds((__attribute__((address_space(1))) const void*)g,
                                   (__attribute__((address_space(3))) void*)l, 16, 0, 0);
}

// ---------------- LayerNorm: fp32 [rows][1024] -> bf16 [rows][1024] ----------------
__global__ __launch_bounds__(256) void ln_k(const float* __restrict__ X,
                                            const float* __restrict__ G,
                                            const float* __restrict__ Bv,
                                            u16* __restrict__ out) {
  const int row = blockIdx.x;
  const int t = threadIdx.x;
  const float4 v = reinterpret_cast<const float4*>(X + (size_t)row * 1024)[t];
  float s = v.x + v.y + v.z + v.w;
  float q = v.x * v.x + v.y * v.y + v.z * v.z + v.w * v.w;
  for (int off = 32; off > 0; off >>= 1) {
    s += __shfl_down(s, off);
    q += __shfl_down(q, off);
  }
  __shared__ float ss[4], qs[4];
  const int w = t >> 6, l = t & 63;
  if (l == 0) { ss[w] = s; qs[w] = q; }
  __syncthreads();
  s = ss[0] + ss[1] + ss[2] + ss[3];
  q = qs[0] + qs[1] + qs[2] + qs[3];
  const float mu = s * (1.0f / 1024.0f);
  const float rs = rsqrtf(q * (1.0f / 1024.0f) - mu * mu + 1e-5f);
  const float4 gv = reinterpret_cast<const float4*>(G)[t];
  const float4 bv = reinterpret_cast<const float4*>(Bv)[t];
  union { u16 u[4]; unsigned long long ll; } pk;
  pk.u[0] = f2bf((v.x - mu) * rs * gv.x + bv.x);
  pk.u[1] = f2bf((v.y - mu) * rs * gv.y + bv.y);
  pk.u[2] = f2bf((v.z - mu) * rs * gv.z + bv.z);
  pk.u[3] = f2bf((v.w - mu) * rs * gv.w + bv.w);
  *reinterpret_cast<unsigned long long*>(out + (size_t)row * 1024 + t * 4) = pk.ll;
}

// ---- merged weight convert+transpose: 12 z-slices of 32x32-block transposes ----
__global__ __launch_bounds__(256) void wconv12_k(const float* __restrict__ Wq,
                                                 const float* __restrict__ Wk,
                                                 const float* __restrict__ Wv,
                                                 const float* __restrict__ Wo,
                                                 const float* __restrict__ W1,
                                                 const float* __restrict__ W2,
                                                 u16* __restrict__ Wqkvt,
                                                 u16* __restrict__ Wot,
                                                 u16* __restrict__ W1t,
                                                 u16* __restrict__ W2t) {
  __shared__ u16 tile[32][33];
  const int z = blockIdx.z;
  const float* W;
  u16* Wt;
  int K, N, n0, k0;
  if (z < 4) {
    W = (z == 0) ? Wq : (z == 1) ? Wk : (z == 2) ? Wv : Wo;
    Wt = (z == 3) ? Wot : (Wqkvt + (size_t)z * 1024 * 1024);
    K = 1024; N = 1024;
    n0 = blockIdx.x * 32; k0 = blockIdx.y * 32;
  } else if (z < 8) {
    W = W1; Wt = W1t; K = 1024; N = 4096;
    n0 = blockIdx.x * 32 + (z - 4) * 1024; k0 = blockIdx.y * 32;
  } else {
    W = W2; Wt = W2t; K = 4096; N = 1024;
    n0 = blockIdx.x * 32; k0 = blockIdx.y * 32 + (z - 8) * 1024;
  }
  const int x = threadIdx.x, y = threadIdx.y;
#pragma unroll
  for (int i = 0; i < 4; ++i)
    tile[y + i * 8][x] = f2bf(W[(size_t)(k0 + y + i * 8) * N + n0 + x]);
  __syncthreads();
#pragma unroll
  for (int i = 0; i < 4; ++i)
    Wt[(size_t)(n0 + y + i * 8) * K + k0 + x] = tile[x][y + i * 8];
}

// ------- GEMM 128x128, BK=64 single-buffer (proj / split-K core) -------------------
template <int EPI>
__global__ __launch_bounds__(256) void gemm_bt64(const u16* __restrict__ A,
                                                 const u16* __restrict__ Bt,
                                                 u16* __restrict__ Cb, float* Cf,
                                                 const float* __restrict__ bias,
                                                 const float* res, int M, int N,
                                                 int K, int kzSplit) {
  __shared__ __align__(16) u16 As[8192];   // [128][64]
  __shared__ __align__(16) u16 Bs[8192];
  const int t = threadIdx.x;
  const int l = t & 63, w = t >> 6;
  const int nbx = N >> 7;
  const int id = blockIdx.x;
  int tiles, tid, kz;
  if (kzSplit) {  // grid = 2 * tiles; kz = id >> 8 (tiles == 256)
    kz = id >> 8;
    tid = id & 255;
    tiles = 256;
  } else {
    kz = 0;
    tid = id;
    tiles = (int)gridDim.x;
  }
  const int qd = tiles >> 3;
  const int swz = (tid & 7) * qd + (tid >> 3);  // XCD swizzle (tiles % 8 == 0)
  const int by = swz / nbx, bx = swz - by * nbx;
  const int Keff = kzSplit ? (K >> 1) : K;
  const int koff = kz * Keff;

  const int scol = ((t & 7) ^ ((t >> 3) & 7)) * 8;
  const u16* gA = A + (size_t)(by * 128 + (t >> 3)) * K + koff + scol;
  const u16* gB = Bt + (size_t)(bx * 128 + (t >> 3)) * K + koff + scol;
  const size_t r32K = (size_t)32 * K;
  const int dst = t * 8;

  const int wr = w >> 1, wc = w & 1;
  const int arow = (wr * 64 + (l & 15)) * 64;
  const int brow = (wc * 64 + (l & 15)) * 64;
  const int ck0 = ((l >> 4) ^ (l & 7)) * 8;
  const int ck1 = ((4 + (l >> 4)) ^ (l & 7)) * 8;

  const f32x4 fz = {0.f, 0.f, 0.f, 0.f};
  f32x4 acc[4][4];
#pragma unroll
  for (int i = 0; i < 4; ++i)
#pragma unroll
    for (int j = 0; j < 4; ++j) acc[i][j] = fz;

  const int nk = Keff >> 6;
  for (int kk = 0; kk < nk; ++kk) {
    __syncthreads();
#pragma unroll
    for (int i = 0; i < 4; ++i) {
      glds16(gA + i * r32K, As + i * 2048 + dst);
      glds16(gB + i * r32K, Bs + i * 2048 + dst);
    }
    gA += 64;
    gB += 64;
    __syncthreads();
#pragma unroll
    for (int ks = 0; ks < 2; ++ks) {
      const int ck = ks ? ck1 : ck0;
      bf16x8 af[4], bv[4];
#pragma unroll
      for (int i = 0; i < 4; ++i)
        af[i] = *reinterpret_cast<const bf16x8*>(&As[arow + i * 1024 + ck]);
#pragma unroll
      for (int j = 0; j < 4; ++j)
        bv[j] = *reinterpret_cast<const bf16x8*>(&Bs[brow + j * 1024 + ck]);
      __builtin_amdgcn_s_setprio(1);
#pragma unroll
      for (int i = 0; i < 4; ++i)
#pragma unroll
        for (int j = 0; j < 4; ++j) acc[i][j] = MFMA16(af[i], bv[j], acc[i][j]);
      __builtin_amdgcn_s_setprio(0);
    }
  }

  const int r0 = by * 128 + wr * 64 + ((l >> 4) << 2);
  const int c0 = bx * 128 + wc * 64 + (l & 15);
  if (EPI == 0) {
    u16* Cp = Cb + (size_t)kz * M * N;
#pragma unroll
    for (int mi = 0; mi < 4; ++mi)
#pragma unroll
      for (int ni = 0; ni < 4; ++ni) {
        const size_t base = (size_t)(r0 + mi * 16) * N + (c0 + ni * 16);
#pragma unroll
        for (int r = 0; r < 4; ++r) Cp[base + (size_t)r * N] = f2bf(acc[mi][ni][r]);
      }
  } else {
#pragma unroll
    for (int mi = 0; mi < 4; ++mi)
#pragma unroll
      for (int ni = 0; ni < 4; ++ni) {
        const int col = c0 + ni * 16;
        const float bb = bias ? bias[col] : 0.0f;
        const size_t base = (size_t)(r0 + mi * 16) * N + col;
#pragma unroll
        for (int r = 0; r < 4; ++r) {
          const size_t idx = base + (size_t)r * N;
          Cf[idx] = res[idx] + acc[mi][ni][r] + bb;
        }
      }
  }
}

// ------- GEMM 128x256, BK=64 single-buffer, 8 waves ---------------------------------
template <int EPI, bool VT>
__global__ __launch_bounds__(512) void gemm_wide(const u16* __restrict__ A,
                                                 const u16* __restrict__ Bt,
                                                 u16* __restrict__ Cb,
                                                 u16* __restrict__ Vt,
                                                 const float* __restrict__ bias,
                                                 int M, int N, int K) {
  __shared__ __align__(16) u16 As[8192];    // [128][64]
  __shared__ __align__(16) u16 Bs[16384];   // [256][64]
  const int t = threadIdx.x;
  const int l = t & 63, w = t >> 6;
  const int nbx = N >> 8;
  const int qd = (int)gridDim.x >> 3;
  const int id = blockIdx.x;
  const int swz = (id & 7) * qd + (id >> 3);  // XCD swizzle (grid % 8 == 0)
  const int by = swz / nbx, bx = swz - by * nbx;

  const int scol = ((t & 7) ^ ((t >> 3) & 7)) * 8;
  const u16* gA = A + (size_t)(by * 128 + (t >> 3)) * K + scol;
  const u16* gB = Bt + (size_t)(bx * 256 + (t >> 3)) * K + scol;
  const size_t r64K = (size_t)64 * K;
  const int dst = t * 8;

  const int wr = w >> 2, wc = w & 3;  // 2M x 4N; wave out 64x64
  const int arow = (wr * 64 + (l & 15)) * 64;
  const int brow = (wc * 64 + (l & 15)) * 64;
  const int ck0 = ((l >> 4) ^ (l & 7)) * 8;
  const int ck1 = ((4 + (l >> 4)) ^ (l & 7)) * 8;

  const f32x4 fz = {0.f, 0.f, 0.f, 0.f};
  f32x4 acc[4][4];
#pragma unroll
  for (int i = 0; i < 4; ++i)
#pragma unroll
    for (int j = 0; j < 4; ++j) acc[i][j] = fz;

  const int nk = K >> 6;
  for (int kk = 0; kk < nk; ++kk) {
    __syncthreads();
    glds16(gA, As + dst);
    glds16(gA + r64K, As + 4096 + dst);
    glds16(gB, Bs + dst);
    glds16(gB + r64K, Bs + 4096 + dst);
    glds16(gB + 2 * r64K, Bs + 8192 + dst);
    glds16(gB + 3 * r64K, Bs + 12288 + dst);
    gA += 64;
    gB += 64;
    __syncthreads();
#pragma unroll
    for (int ks = 0; ks < 2; ++ks) {
      const int ck = ks ? ck1 : ck0;
      bf16x8 af[4], bv[4];
#pragma unroll
      for (int i = 0; i < 4; ++i)
        af[i] = *reinterpret_cast<const bf16x8*>(&As[arow + i * 1024 + ck]);
#pragma unroll
      for (int j = 0; j < 4; ++j)
        bv[j] = *reinterpret_cast<const bf16x8*>(&Bs[brow + j * 1024 + ck]);
      __builtin_amdgcn_s_setprio(1);
#pragma unroll
      for (int i = 0; i < 4; ++i)
#pragma unroll
        for (int j = 0; j < 4; ++j) acc[i][j] = MFMA16(af[i], bv[j], acc[i][j]);
      __builtin_amdgcn_s_setprio(0);
    }
  }

  const int r0 = by * 128 + wr * 64 + ((l >> 4) << 2);
  const int c0 = bx * 256 + wc * 64 + (l & 15);
  if (VT && bx >= 8) {  // V block: write transposed into Vt[bh][dk][t]
    const int hh = (bx - 8) * 4 + wc;
    const int b = by >> 4;
    const size_t hb = ((size_t)b * 16 + hh) * 64;
#pragma unroll
    for (int mi = 0; mi < 4; ++mi) {
      const int t0 = ((by & 15) * 128) + wr * 64 + ((l >> 4) << 2) + mi * 16;
#pragma unroll
      for (int ni = 0; ni < 4; ++ni) {
        const int dk = ni * 16 + (l & 15);
        union { u16 u[4]; unsigned long long ll; } pk;
#pragma unroll
        for (int r = 0; r < 4; ++r) pk.u[r] = f2bf(acc[mi][ni][r]);
        *reinterpret_cast<unsigned long long*>(&Vt[(hb + dk) * 2048 + t0]) = pk.ll;
      }
    }
  } else {
#pragma unroll
    for (int mi = 0; mi < 4; ++mi)
#pragma unroll
      for (int ni = 0; ni < 4; ++ni) {
        const int col = c0 + ni * 16;
        const size_t base = (size_t)(r0 + mi * 16) * N + col;
        if (EPI == 0) {
#pragma unroll
          for (int r = 0; r < 4; ++r) Cb[base + (size_t)r * N] = f2bf(acc[mi][ni][r]);
        } else {
          const float bb = bias[col];
#pragma unroll
          for (int r = 0; r < 4; ++r) {
            const float x = acc[mi][ni][r] + bb;
            const float gl = 0.5f * x * (1.0f + erff(x * 0.70710678118654752f));
            Cb[base + (size_t)r * N] = f2bf(gl);
          }
        }
      }
  }
}

// ---------------- reduce: out += P0 + P1 + bias  (4096x1024 f32) ----------------
__global__ __launch_bounds__(256) void reduce_k(float* __restrict__ out,
                                                const u16* __restrict__ P0,
                                                const u16* __restrict__ P1,
                                                const float* __restrict__ bias) {
  const int q0 = blockIdx.x * 256 + threadIdx.x;
#pragma unroll
  for (int it = 0; it < 2; ++it) {
    const size_t q = ((size_t)q0 + (size_t)it * 524288) * 4;
    float4 o = *reinterpret_cast<float4*>(&out[q]);
    const ushort4 a = *reinterpret_cast<const ushort4*>(&P0[q]);
    const ushort4 b = *reinterpret_cast<const ushort4*>(&P1[q]);
    const float4 bb = *reinterpret_cast<const float4*>(&bias[q & 1023]);
    o.x += bf2f(a.x) + bf2f(b.x) + bb.x;
    o.y += bf2f(a.y) + bf2f(b.y) + bb.y;
    o.z += bf2f(a.z) + bf2f(b.z) + bb.z;
    o.w += bf2f(a.w) + bf2f(b.w) + bb.w;
    *reinterpret_cast<float4*>(&out[q]) = o;
  }
}

// ---------------- causal flash attention (LDS-staged K/V, 8 waves, 128-row qblk) ----
__global__ __launch_bounds__(512) void attn_k(const u16* __restrict__ QKV,
                                              const u16* __restrict__ Vt,
                                              u16* __restrict__ O) {
  __shared__ __align__(16) u16 Kbuf[2][4096];
  __shared__ __align__(16) u16 Vbuf[2][4096];
  __shared__ __align__(16) u16 Plds[8][16][68];
  const int t = threadIdx.x;
  const int l = t & 63, w = t >> 6;
  const int g = l >> 4, c = l & 15;
  const int pj = blockIdx.x, bh = blockIdx.y;
  const int b = bh >> 4, h = bh & 15;
  const u16* Kp = QKV + (size_t)b * 2048 * 3072 + 1024 + h * 64;
  const u16* Vp = Vt + (size_t)bh * 64 * 2048;
  const f32x4 fz = {0.f, 0.f, 0.f, 0.f};
  const int srow = t >> 3;
  const int scol = ((t & 7) ^ (srow & 7)) * 8;
  u16* kdst0 = &Kbuf[0][w * 512];
  u16* kdst1 = &Kbuf[1][w * 512];
  u16* vdst0 = &Vbuf[0][w * 512];
  u16* vdst1 = &Vbuf[1][w * 512];
  const int ca = (g ^ (c & 7)) * 8;
  const int cb = ((g + 4) ^ (c & 7)) * 8;

#pragma unroll 1
  for (int hf = 0; hf < 2; ++hf) {
    const int qblk = hf ? (15 - pj) : pj;
    const int nkt = 2 * qblk + 2;
    const int qrow0 = qblk * 128 + w * 16;
    const size_t qoff = (size_t)(b * 2048 + qrow0 + c) * 3072 + h * 64 + g * 8;
    const bf16x8 qf0 = *reinterpret_cast<const bf16x8*>(&QKV[qoff]);
    const bf16x8 qf1 = *reinterpret_cast<const bf16x8*>(&QKV[qoff + 32]);
    f32x4 o[4];
    float m[4], lsl[4];
#pragma unroll
    for (int f = 0; f < 4; ++f) o[f] = fz;
#pragma unroll
    for (int r = 0; r < 4; ++r) {
      m[r] = -__builtin_inff();
      lsl[r] = 0.f;
    }
    glds16(Kp + (size_t)srow * 3072 + scol, kdst0);
    glds16(Vp + (size_t)srow * 2048 + scol, vdst0);
    __syncthreads();
    int cur = 0;

#pragma unroll 1
    for (int kt = 0; kt < nkt; ++kt) {
      const int key0 = kt * 64;
      if (kt + 1 < nkt) {
        const int kn = key0 + 64;
        glds16(Kp + (size_t)(kn + srow) * 3072 + scol, cur ? kdst0 : kdst1);
        glds16(Vp + (size_t)srow * 2048 + kn + scol, cur ? vdst0 : vdst1);
      }
      if (key0 <= qrow0 + 15) {
        const u16* Kc = Kbuf[cur];
        const u16* Vc = Vbuf[cur];
        f32x4 s4[4];
        __builtin_amdgcn_s_setprio(1);
#pragma unroll
        for (int kq = 0; kq < 4; ++kq) {
          const int rb = (c + 16 * kq) * 64;
          const bf16x8 k0 = *reinterpret_cast<const bf16x8*>(&Kc[rb + ca]);
          const bf16x8 k1 = *reinterpret_cast<const bf16x8*>(&Kc[rb + cb]);
          s4[kq] = MFMA16(qf0, k0, fz);
          s4[kq] = MFMA16(qf1, k1, s4[kq]);
        }
        __builtin_amdgcn_s_setprio(0);
        bf16x8 vf[8];
#pragma unroll
        for (int f = 0; f < 4; ++f) {
          const int rb = (c + 16 * f) * 64;
          vf[f * 2] = *reinterpret_cast<const bf16x8*>(&Vc[rb + ca]);
          vf[f * 2 + 1] = *reinterpret_cast<const bf16x8*>(&Vc[rb + cb]);
        }
        const bool maskT = (kt >= nkt - 2);
        float xs[4][4];
        float mx4 = -__builtin_inff();
#pragma unroll
        for (int r = 0; r < 4; ++r) {
          const int qg = qrow0 + g * 4 + r;
          xs[r][0] = s4[0][r] * 0.125f;
          xs[r][1] = s4[1][r] * 0.125f;
          xs[r][2] = s4[2][r] * 0.125f;
          xs[r][3] = s4[3][r] * 0.125f;
          if (maskT) {
            if (key0 + c > qg) xs[r][0] = -__builtin_inff();
            if (key0 + 16 + c > qg) xs[r][1] = -__builtin_inff();
            if (key0 + 32 + c > qg) xs[r][2] = -__builtin_inff();
            if (key0 + 48 + c > qg) xs[r][3] = -__builtin_inff();
          }
          const float a0 = fmaxf(xs[r][0], xs[r][1]);
          const float a1 = fmaxf(xs[r][2], xs[r][3]);
          mx4 = fmaxf(mx4, fmaxf(a0, a1) - m[r]);
        }
        if (!__all(mx4 <= 8.0f)) {
#pragma unroll
          for (int r = 0; r < 4; ++r) {
            float tm = fmaxf(fmaxf(xs[r][0], xs[r][1]), fmaxf(xs[r][2], xs[r][3]));
            tm = fmaxf(tm, __shfl_xor(tm, 1, 16));
            tm = fmaxf(tm, __shfl_xor(tm, 2, 16));
            tm = fmaxf(tm, __shfl_xor(tm, 4, 16));
            tm = fmaxf(tm, __shfl_xor(tm, 8, 16));
            const float mn = fmaxf(m[r], tm);
            const float scl = __expf(m[r] - mn);
            lsl[r] *= scl;
            m[r] = mn;
            o[0][r] *= scl;
            o[1][r] *= scl;
            o[2][r] *= scl;
            o[3][r] *= scl;
          }
        }
#pragma unroll
        for (int r = 0; r < 4; ++r) {
          const float p0 = __expf(xs[r][0] - m[r]), p1 = __expf(xs[r][1] - m[r]);
          const float p2 = __expf(xs[r][2] - m[r]), p3 = __expf(xs[r][3] - m[r]);
          lsl[r] += (p0 + p1) + (p2 + p3);
          const int pr = g * 4 + r;
          Plds[w][pr][c] = f2bf(p0);
          Plds[w][pr][c + 16] = f2bf(p1);
          Plds[w][pr][c + 32] = f2bf(p2);
          Plds[w][pr][c + 48] = f2bf(p3);
        }
        asm volatile("" ::: "memory");
        const bf16x8 pa0 = *reinterpret_cast<const bf16x8*>(&Plds[w][c][g * 8]);
        const bf16x8 pa1 = *reinterpret_cast<const bf16x8*>(&Plds[w][c][32 + g * 8]);
        __builtin_amdgcn_s_setprio(1);
#pragma unroll
        for (int f = 0; f < 4; ++f) {
          o[f] = MFMA16(pa0, vf[f * 2], o[f]);
          o[f] = MFMA16(pa1, vf[f * 2 + 1], o[f]);
        }
        __builtin_amdgcn_s_setprio(0);
      }
      __syncthreads();
      cur ^= 1;
    }

    u16* op = O + (size_t)(b * 2048 + qrow0 + g * 4) * 1024 + h * 64 + c;
#pragma unroll
    for (int r = 0; r < 4; ++r) {
      float ls = lsl[r];
      ls += __shfl_xor(ls, 1, 16);
      ls += __shfl_xor(ls, 2, 16);
      ls += __shfl_xor(ls, 4, 16);
      ls += __shfl_xor(ls, 8, 16);
      const float inv = 1.0f / ls;
#pragma unroll
      for (int f = 0; f < 4; ++f) op[(size_t)r * 1024 + f * 16] = f2bf(o[f][r] * inv);
    }
  }
}

// ---------------- launcher ----------------
extern "C" void kernel_launch(void* const* d_in, const int* in_sizes, int n_in,
                              void* d_out, int out_size, void* d_ws, size_t ws_size,
                              hipStream_t stream) {
  const float* H   = (const float*)d_in[0];
  const float* Wq  = (const float*)d_in[1];
  const float* Wk  = (const float*)d_in[2];
  const float* Wv  = (const float*)d_in[3];
  const float* Wo  = (const float*)d_in[4];
  const float* g1  = (const float*)d_in[5];
  const float* be1 = (const float*)d_in[6];
  const float* g2  = (const float*)d_in[7];
  const float* be2 = (const float*)d_in[8];
  const float* W1  = (const float*)d_in[9];
  const float* bb1 = (const float*)d_in[10];
  const float* W2  = (const float*)d_in[11];
  const float* bb2 = (const float*)d_in[12];
  float* out = (float*)d_out;

  if (ws_size < (size_t)67108864) return;  // need 64 MiB
  char* ws = (char*)d_ws;
  u16* Wqkvt = (u16*)(ws + 0);
  u16* Xattn = (u16*)(ws + 6291456);
  u16* QKV   = (u16*)(ws + 14680064);
  u16* Vt    = (u16*)(ws + 39845888);
  u16* Wot   = (u16*)(ws + 48234496);
  u16* W1t   = (u16*)(ws + 50331648);
  u16* W2t   = (u16*)(ws + 58720256);
  u16* Hmlp  = (u16*)(ws + 0);
  u16* Xln2  = Vt;
  u16* Pp    = (u16*)(ws + 39845888);

  wconv12_k<<<dim3(32, 32, 12), dim3(32, 8), 0, stream>>>(Wq, Wk, Wv, Wo, W1, W2,
                                                          Wqkvt, Wot, W1t, W2t);
  ln_k<<<4096, 256, 0, stream>>>(H, g1, be1, Xattn);
  gemm_wide<0, true><<<384, 512, 0, stream>>>(Xattn, Wqkvt, QKV, Vt, nullptr,
                                              4096, 3072, 1024);
  attn_k<<<dim3(8, 32), 512, 0, stream>>>(QKV, Vt, Xattn);
  gemm_bt64<2><<<256, 256, 0, stream>>>(Xattn, Wot, nullptr, out, nullptr, H,
                                        4096, 1024, 1024, 0);
  ln_k<<<4096, 256, 0, stream>>>(out, g2, be2, Xln2);
  gemm_wide<1, false><<<512, 512, 0, stream>>>(Xln2, W1t, Hmlp, nullptr, bb1,
                                               4096, 4096, 1024);
  gemm_bt64<0><<<512, 256, 0, stream>>>(Hmlp, W2t, Pp, nullptr, nullptr, nullptr,
                                        4096, 1024, 4096, 1);
  reduce_k<<<2048, 256, 0, stream>>>(out, Pp, Pp + (size_t)4096 * 1024, bb2);
}

// Round 21
// 234.643 us; speedup vs baseline: 1.0820x; 1.0053x over previous
//
#include <hip/hip_runtime.h>
#include <hip/hip_bf16.h>
#include <math.h>

typedef unsigned short u16;
typedef __bf16 bf16x8 __attribute__((ext_vector_type(8)));
typedef float f32x4 __attribute__((ext_vector_type(4)));
typedef u16 u16x8 __attribute__((ext_vector_type(8)));

#define MFMA16(a, b, c) __builtin_amdgcn_mfma_f32_16x16x32_bf16((a), (b), (c), 0, 0, 0)

__device__ __forceinline__ u16 f2bf(float f) {
  unsigned u = __float_as_uint(f);
  u += 0x7fffu + ((u >> 16) & 1u);
  return (u16)(u >> 16);
}
__device__ __forceinline__ float bf2f(u16 u) {
  return __uint_as_float((unsigned)u << 16);
}

__device__ __forceinline__ void glds16(const u16* g, u16* l) {
  __builtin_amdgcn_global_load_lds((__attribute__((address_space(1))) const void*)g,
                                   (__attribute__((address_space(3))) void*)l, 16, 0, 0);
}

// ---------------- LayerNorm: fp32 [rows][1024] -> bf16 [rows][1024] ----------------
__global__ __launch_bounds__(256) void ln_k(const float* __restrict__ X,
                                            const float* __restrict__ G,
                                            const float* __restrict__ Bv,
                                            u16* __restrict__ out) {
  const int row = blockIdx.x;
  const int t = threadIdx.x;
  const float4 v = reinterpret_cast<const float4*>(X + (size_t)row * 1024)[t];
  float s = v.x + v.y + v.z + v.w;
  float q = v.x * v.x + v.y * v.y + v.z * v.z + v.w * v.w;
  for (int off = 32; off > 0; off >>= 1) {
    s += __shfl_down(s, off);
    q += __shfl_down(q, off);
  }
  __shared__ float ss[4], qs[4];
  const int w = t >> 6, l = t & 63;
  if (l == 0) { ss[w] = s; qs[w] = q; }
  __syncthreads();
  s = ss[0] + ss[1] + ss[2] + ss[3];
  q = qs[0] + qs[1] + qs[2] + qs[3];
  const float mu = s * (1.0f / 1024.0f);
  const float rs = rsqrtf(q * (1.0f / 1024.0f) - mu * mu + 1e-5f);
  const float4 gv = reinterpret_cast<const float4*>(G)[t];
  const float4 bv = reinterpret_cast<const float4*>(Bv)[t];
  union { u16 u[4]; unsigned long long ll; } pk;
  pk.u[0] = f2bf((v.x - mu) * rs * gv.x + bv.x);
  pk.u[1] = f2bf((v.y - mu) * rs * gv.y + bv.y);
  pk.u[2] = f2bf((v.z - mu) * rs * gv.z + bv.z);
  pk.u[3] = f2bf((v.w - mu) * rs * gv.w + bv.w);
  *reinterpret_cast<unsigned long long*>(out + (size_t)row * 1024 + t * 4) = pk.ll;
}

// ---- merged weight convert+transpose: 12 z-slices of 32x32-block transposes ----
__global__ __launch_bounds__(256) void wconv12_k(const float* __restrict__ Wq,
                                                 const float* __restrict__ Wk,
                                                 const float* __restrict__ Wv,
                                                 const float* __restrict__ Wo,
                                                 const float* __restrict__ W1,
                                                 const float* __restrict__ W2,
                                                 u16* __restrict__ Wqkvt,
                                                 u16* __restrict__ Wot,
                                                 u16* __restrict__ W1t,
                                                 u16* __restrict__ W2t) {
  __shared__ u16 tile[32][33];
  const int z = blockIdx.z;
  const float* W;
  u16* Wt;
  int K, N, n0, k0;
  if (z < 4) {
    W = (z == 0) ? Wq : (z == 1) ? Wk : (z == 2) ? Wv : Wo;
    Wt = (z == 3) ? Wot : (Wqkvt + (size_t)z * 1024 * 1024);
    K = 1024; N = 1024;
    n0 = blockIdx.x * 32; k0 = blockIdx.y * 32;
  } else if (z < 8) {
    W = W1; Wt = W1t; K = 1024; N = 4096;
    n0 = blockIdx.x * 32 + (z - 4) * 1024; k0 = blockIdx.y * 32;
  } else {
    W = W2; Wt = W2t; K = 4096; N = 1024;
    n0 = blockIdx.x * 32; k0 = blockIdx.y * 32 + (z - 8) * 1024;
  }
  const int x = threadIdx.x, y = threadIdx.y;
#pragma unroll
  for (int i = 0; i < 4; ++i)
    tile[y + i * 8][x] = f2bf(W[(size_t)(k0 + y + i * 8) * N + n0 + x]);
  __syncthreads();
#pragma unroll
  for (int i = 0; i < 4; ++i)
    Wt[(size_t)(n0 + y + i * 8) * K + k0 + x] = tile[x][y + i * 8];
}

// ------- GEMM 128x128, BK=64 single-buffer (proj / split-K core) -------------------
template <int EPI>
__global__ __launch_bounds__(256) void gemm_bt64(const u16* __restrict__ A,
                                                 const u16* __restrict__ Bt,
                                                 u16* __restrict__ Cb, float* Cf,
                                                 const float* __restrict__ bias,
                                                 const float* res, int M, int N,
                                                 int K, int kzSplit) {
  __shared__ __align__(16) u16 As[8192];   // [128][64]
  __shared__ __align__(16) u16 Bs[8192];
  const int t = threadIdx.x;
  const int l = t & 63, w = t >> 6;
  const int nbx = N >> 7;
  const int id = blockIdx.x;
  int tiles, tid, kz;
  if (kzSplit) {  // grid = 2 * tiles; kz = id >> 8 (tiles == 256)
    kz = id >> 8;
    tid = id & 255;
    tiles = 256;
  } else {
    kz = 0;
    tid = id;
    tiles = (int)gridDim.x;
  }
  const int qd = tiles >> 3;
  const int swz = (tid & 7) * qd + (tid >> 3);  // XCD swizzle (tiles % 8 == 0)
  const int by = swz / nbx, bx = swz - by * nbx;
  const int Keff = kzSplit ? (K >> 1) : K;
  const int koff = kz * Keff;

  const int scol = ((t & 7) ^ ((t >> 3) & 7)) * 8;
  const u16* gA = A + (size_t)(by * 128 + (t >> 3)) * K + koff + scol;
  const u16* gB = Bt + (size_t)(bx * 128 + (t >> 3)) * K + koff + scol;
  const size_t r32K = (size_t)32 * K;
  const int dst = t * 8;

  const int wr = w >> 1, wc = w & 1;
  const int arow = (wr * 64 + (l & 15)) * 64;
  const int brow = (wc * 64 + (l & 15)) * 64;
  const int ck0 = ((l >> 4) ^ (l & 7)) * 8;
  const int ck1 = ((4 + (l >> 4)) ^ (l & 7)) * 8;

  const f32x4 fz = {0.f, 0.f, 0.f, 0.f};
  f32x4 acc[4][4];
#pragma unroll
  for (int i = 0; i < 4; ++i)
#pragma unroll
    for (int j = 0; j < 4; ++j) acc[i][j] = fz;

  const int nk = Keff >> 6;
  for (int kk = 0; kk < nk; ++kk) {
    __syncthreads();
#pragma unroll
    for (int i = 0; i < 4; ++i) {
      glds16(gA + i * r32K, As + i * 2048 + dst);
      glds16(gB + i * r32K, Bs + i * 2048 + dst);
    }
    gA += 64;
    gB += 64;
    __syncthreads();
#pragma unroll
    for (int ks = 0; ks < 2; ++ks) {
      const int ck = ks ? ck1 : ck0;
      bf16x8 af[4], bv[4];
#pragma unroll
      for (int i = 0; i < 4; ++i)
        af[i] = *reinterpret_cast<const bf16x8*>(&As[arow + i * 1024 + ck]);
#pragma unroll
      for (int j = 0; j < 4; ++j)
        bv[j] = *reinterpret_cast<const bf16x8*>(&Bs[brow + j * 1024 + ck]);
      __builtin_amdgcn_s_setprio(1);
#pragma unroll
      for (int i = 0; i < 4; ++i)
#pragma unroll
        for (int j = 0; j < 4; ++j) acc[i][j] = MFMA16(af[i], bv[j], acc[i][j]);
      __builtin_amdgcn_s_setprio(0);
    }
  }

  const int r0 = by * 128 + wr * 64 + ((l >> 4) << 2);
  const int c0 = bx * 128 + wc * 64 + (l & 15);
  if (EPI == 0) {
    u16* Cp = Cb + (size_t)kz * M * N;
#pragma unroll
    for (int mi = 0; mi < 4; ++mi)
#pragma unroll
      for (int ni = 0; ni < 4; ++ni) {
        const size_t base = (size_t)(r0 + mi * 16) * N + (c0 + ni * 16);
#pragma unroll
        for (int r = 0; r < 4; ++r) Cp[base + (size_t)r * N] = f2bf(acc[mi][ni][r]);
      }
  } else {
#pragma unroll
    for (int mi = 0; mi < 4; ++mi)
#pragma unroll
      for (int ni = 0; ni < 4; ++ni) {
        const int col = c0 + ni * 16;
        const float bb = bias ? bias[col] : 0.0f;
        const size_t base = (size_t)(r0 + mi * 16) * N + col;
#pragma unroll
        for (int r = 0; r < 4; ++r) {
          const size_t idx = base + (size_t)r * N;
          Cf[idx] = res[idx] + acc[mi][ni][r] + bb;
        }
      }
  }
}

// ------- QKV GEMM 128x192, BK=64, 8 waves (2Mx4N, wave 64x48) ---------------------
// N=3072/192 -> 512 tiles = uniform 2 blocks/CU (fixes 384-block grid quantization).
// Per-16-col-fragment V check (2048 boundary is 16-aligned, wave-uniform branch):
// V fragments write transposed into Vt[32][64][2048] (4 rows -> one 8B store).
__global__ __launch_bounds__(512) void gemm_qkv(const u16* __restrict__ A,
                                                const u16* __restrict__ Bt,
                                                u16* __restrict__ Cb,
                                                u16* __restrict__ Vt,
                                                int M, int N, int K) {
  __shared__ __align__(16) u16 As[8192];    // [128][64]
  __shared__ __align__(16) u16 Bs[12288];   // [192][64]
  const int t = threadIdx.x;
  const int l = t & 63, w = t >> 6;
  const int nbx = 16;  // N/192
  const int qd = (int)gridDim.x >> 3;
  const int id = blockIdx.x;
  const int swz = (id & 7) * qd + (id >> 3);  // XCD swizzle (grid % 8 == 0)
  const int by = swz / nbx, bx = swz - by * nbx;

  const int scol = ((t & 7) ^ ((t >> 3) & 7)) * 8;
  const u16* gA = A + (size_t)(by * 128 + (t >> 3)) * K + scol;
  const u16* gB = Bt + (size_t)(bx * 192 + (t >> 3)) * K + scol;
  const size_t r64K = (size_t)64 * K;
  const int dst = t * 8;

  const int wr = w >> 2, wc = w & 3;  // 2M x 4N; wave out 64x48
  const int arow = (wr * 64 + (l & 15)) * 64;
  const int brow = (wc * 48 + (l & 15)) * 64;
  const int ck0 = ((l >> 4) ^ (l & 7)) * 8;
  const int ck1 = ((4 + (l >> 4)) ^ (l & 7)) * 8;

  const f32x4 fz = {0.f, 0.f, 0.f, 0.f};
  f32x4 acc[4][3];
#pragma unroll
  for (int i = 0; i < 4; ++i)
#pragma unroll
    for (int j = 0; j < 3; ++j) acc[i][j] = fz;

  const int nk = K >> 6;
  for (int kk = 0; kk < nk; ++kk) {
    __syncthreads();
    glds16(gA, As + dst);
    glds16(gA + r64K, As + 4096 + dst);
    glds16(gB, Bs + dst);
    glds16(gB + r64K, Bs + 4096 + dst);
    glds16(gB + 2 * r64K, Bs + 8192 + dst);
    gA += 64;
    gB += 64;
    __syncthreads();
#pragma unroll
    for (int ks = 0; ks < 2; ++ks) {
      const int ck = ks ? ck1 : ck0;
      bf16x8 af[4], bv[3];
#pragma unroll
      for (int i = 0; i < 4; ++i)
        af[i] = *reinterpret_cast<const bf16x8*>(&As[arow + i * 1024 + ck]);
#pragma unroll
      for (int j = 0; j < 3; ++j)
        bv[j] = *reinterpret_cast<const bf16x8*>(&Bs[brow + j * 1024 + ck]);
      __builtin_amdgcn_s_setprio(1);
#pragma unroll
      for (int i = 0; i < 4; ++i)
#pragma unroll
        for (int j = 0; j < 3; ++j) acc[i][j] = MFMA16(af[i], bv[j], acc[i][j]);
      __builtin_amdgcn_s_setprio(0);
    }
  }

  const int r0 = by * 128 + wr * 64 + ((l >> 4) << 2);
  const int b = (by * 128) >> 11;  // 2048-row batch (tile never straddles)
#pragma unroll
  for (int mi = 0; mi < 4; ++mi) {
    const int row = r0 + mi * 16;
#pragma unroll
    for (int ni = 0; ni < 3; ++ni) {
      const int colblk = bx * 192 + wc * 48 + ni * 16;  // wave-uniform
      const int col = colblk + (l & 15);
      if (colblk >= 2048) {  // V fragment -> transposed Vt write
        const int h = (col - 2048) >> 6;
        const int dk = (col - 2048) & 63;
        const int tt = row - b * 2048;
        union { u16 u[4]; unsigned long long ll; } pk;
#pragma unroll
        for (int r = 0; r < 4; ++r) pk.u[r] = f2bf(acc[mi][ni][r]);
        *reinterpret_cast<unsigned long long*>(
            &Vt[(((size_t)b * 16 + h) * 64 + dk) * 2048 + tt]) = pk.ll;
      } else {
        const size_t base = (size_t)row * N + col;
#pragma unroll
        for (int r = 0; r < 4; ++r) Cb[base + (size_t)r * N] = f2bf(acc[mi][ni][r]);
      }
    }
  }
}

// ------- GEMM 128x256, BK=64 single-buffer, 8 waves (MLP1) --------------------------
template <int EPI>
__global__ __launch_bounds__(512) void gemm_wide(const u16* __restrict__ A,
                                                 const u16* __restrict__ Bt,
                                                 u16* __restrict__ Cb,
                                                 const float* __restrict__ bias,
                                                 int M, int N, int K) {
  __shared__ __align__(16) u16 As[8192];    // [128][64]
  __shared__ __align__(16) u16 Bs[16384];   // [256][64]
  const int t = threadIdx.x;
  const int l = t & 63, w = t >> 6;
  const int nbx = N >> 8;
  const int qd = (int)gridDim.x >> 3;
  const int id = blockIdx.x;
  const int swz = (id & 7) * qd + (id >> 3);  // XCD swizzle (grid % 8 == 0)
  const int by = swz / nbx, bx = swz - by * nbx;

  const int scol = ((t & 7) ^ ((t >> 3) & 7)) * 8;
  const u16* gA = A + (size_t)(by * 128 + (t >> 3)) * K + scol;
  const u16* gB = Bt + (size_t)(bx * 256 + (t >> 3)) * K + scol;
  const size_t r64K = (size_t)64 * K;
  const int dst = t * 8;

  const int wr = w >> 2, wc = w & 3;  // 2M x 4N; wave out 64x64
  const int arow = (wr * 64 + (l & 15)) * 64;
  const int brow = (wc * 64 + (l & 15)) * 64;
  const int ck0 = ((l >> 4) ^ (l & 7)) * 8;
  const int ck1 = ((4 + (l >> 4)) ^ (l & 7)) * 8;

  const f32x4 fz = {0.f, 0.f, 0.f, 0.f};
  f32x4 acc[4][4];
#pragma unroll
  for (int i = 0; i < 4; ++i)
#pragma unroll
    for (int j = 0; j < 4; ++j) acc[i][j] = fz;

  const int nk = K >> 6;
  for (int kk = 0; kk < nk; ++kk) {
    __syncthreads();
    glds16(gA, As + dst);
    glds16(gA + r64K, As + 4096 + dst);
    glds16(gB, Bs + dst);
    glds16(gB + r64K, Bs + 4096 + dst);
    glds16(gB + 2 * r64K, Bs + 8192 + dst);
    glds16(gB + 3 * r64K, Bs + 12288 + dst);
    gA += 64;
    gB += 64;
    __syncthreads();
#pragma unroll
    for (int ks = 0; ks < 2; ++ks) {
      const int ck = ks ? ck1 : ck0;
      bf16x8 af[4], bv[4];
#pragma unroll
      for (int i = 0; i < 4; ++i)
        af[i] = *reinterpret_cast<const bf16x8*>(&As[arow + i * 1024 + ck]);
#pragma unroll
      for (int j = 0; j < 4; ++j)
        bv[j] = *reinterpret_cast<const bf16x8*>(&Bs[brow + j * 1024 + ck]);
      __builtin_amdgcn_s_setprio(1);
#pragma unroll
      for (int i = 0; i < 4; ++i)
#pragma unroll
        for (int j = 0; j < 4; ++j) acc[i][j] = MFMA16(af[i], bv[j], acc[i][j]);
      __builtin_amdgcn_s_setprio(0);
    }
  }

  const int r0 = by * 128 + wr * 64 + ((l >> 4) << 2);
  const int c0 = bx * 256 + wc * 64 + (l & 15);
#pragma unroll
  for (int mi = 0; mi < 4; ++mi)
#pragma unroll
    for (int ni = 0; ni < 4; ++ni) {
      const int col = c0 + ni * 16;
      const size_t base = (size_t)(r0 + mi * 16) * N + col;
      if (EPI == 0) {
#pragma unroll
        for (int r = 0; r < 4; ++r) Cb[base + (size_t)r * N] = f2bf(acc[mi][ni][r]);
      } else {
        const float bb = bias[col];
#pragma unroll
        for (int r = 0; r < 4; ++r) {
          const float x = acc[mi][ni][r] + bb;
          const float gl = 0.5f * x * (1.0f + erff(x * 0.70710678118654752f));
          Cb[base + (size_t)r * N] = f2bf(gl);
        }
      }
    }
}

// ---------------- reduce: out += P0 + P1 + bias  (4096x1024 f32) ----------------
__global__ __launch_bounds__(256) void reduce_k(float* __restrict__ out,
                                                const u16* __restrict__ P0,
                                                const u16* __restrict__ P1,
                                                const float* __restrict__ bias) {
  const int q0 = blockIdx.x * 256 + threadIdx.x;
#pragma unroll
  for (int it = 0; it < 2; ++it) {
    const size_t q = ((size_t)q0 + (size_t)it * 524288) * 4;
    float4 o = *reinterpret_cast<float4*>(&out[q]);
    const ushort4 a = *reinterpret_cast<const ushort4*>(&P0[q]);
    const ushort4 b = *reinterpret_cast<const ushort4*>(&P1[q]);
    const float4 bb = *reinterpret_cast<const float4*>(&bias[q & 1023]);
    o.x += bf2f(a.x) + bf2f(b.x) + bb.x;
    o.y += bf2f(a.y) + bf2f(b.y) + bb.y;
    o.z += bf2f(a.z) + bf2f(b.z) + bb.z;
    o.w += bf2f(a.w) + bf2f(b.w) + bb.w;
    *reinterpret_cast<float4*>(&out[q]) = o;
  }
}

// ---------------- causal flash attention (LDS-staged K/V, 8 waves, 128-row qblk) ----
__global__ __launch_bounds__(512) void attn_k(const u16* __restrict__ QKV,
                                              const u16* __restrict__ Vt,
                                              u16* __restrict__ O) {
  __shared__ __align__(16) u16 Kbuf[2][4096];
  __shared__ __align__(16) u16 Vbuf[2][4096];
  __shared__ __align__(16) u16 Plds[8][16][68];
  const int t = threadIdx.x;
  const int l = t & 63, w = t >> 6;
  const int g = l >> 4, c = l & 15;
  const int pj = blockIdx.x, bh = blockIdx.y;
  const int b = bh >> 4, h = bh & 15;
  const u16* Kp = QKV + (size_t)b * 2048 * 3072 + 1024 + h * 64;
  const u16* Vp = Vt + (size_t)bh * 64 * 2048;
  const f32x4 fz = {0.f, 0.f, 0.f, 0.f};
  const int srow = t >> 3;
  const int scol = ((t & 7) ^ (srow & 7)) * 8;
  u16* kdst0 = &Kbuf[0][w * 512];
  u16* kdst1 = &Kbuf[1][w * 512];
  u16* vdst0 = &Vbuf[0][w * 512];
  u16* vdst1 = &Vbuf[1][w * 512];
  const int ca = (g ^ (c & 7)) * 8;
  const int cb = ((g + 4) ^ (c & 7)) * 8;

#pragma unroll 1
  for (int hf = 0; hf < 2; ++hf) {
    const int qblk = hf ? (15 - pj) : pj;
    const int nkt = 2 * qblk + 2;
    const int qrow0 = qblk * 128 + w * 16;
    const size_t qoff = (size_t)(b * 2048 + qrow0 + c) * 3072 + h * 64 + g * 8;
    const bf16x8 qf0 = *reinterpret_cast<const bf16x8*>(&QKV[qoff]);
    const bf16x8 qf1 = *reinterpret_cast<const bf16x8*>(&QKV[qoff + 32]);
    f32x4 o[4];
    float m[4], lsl[4];
#pragma unroll
    for (int f = 0; f < 4; ++f) o[f] = fz;
#pragma unroll
    for (int r = 0; r < 4; ++r) {
      m[r] = -__builtin_inff();
      lsl[r] = 0.f;
    }
    glds16(Kp + (size_t)srow * 3072 + scol, kdst0);
    glds16(Vp + (size_t)srow * 2048 + scol, vdst0);
    __syncthreads();
    int cur = 0;

#pragma unroll 1
    for (int kt = 0; kt < nkt; ++kt) {
      const int key0 = kt * 64;
      if (kt + 1 < nkt) {
        const int kn = key0 + 64;
        glds16(Kp + (size_t)(kn + srow) * 3072 + scol, cur ? kdst0 : kdst1);
        glds16(Vp + (size_t)srow * 2048 + kn + scol, cur ? vdst0 : vdst1);
      }
      if (key0 <= qrow0 + 15) {
        const u16* Kc = Kbuf[cur];
        const u16* Vc = Vbuf[cur];
        f32x4 s4[4];
        __builtin_amdgcn_s_setprio(1);
#pragma unroll
        for (int kq = 0; kq < 4; ++kq) {
          const int rb = (c + 16 * kq) * 64;
          const bf16x8 k0 = *reinterpret_cast<const bf16x8*>(&Kc[rb + ca]);
          const bf16x8 k1 = *reinterpret_cast<const bf16x8*>(&Kc[rb + cb]);
          s4[kq] = MFMA16(qf0, k0, fz);
          s4[kq] = MFMA16(qf1, k1, s4[kq]);
        }
        __builtin_amdgcn_s_setprio(0);
        bf16x8 vf[8];
#pragma unroll
        for (int f = 0; f < 4; ++f) {
          const int rb = (c + 16 * f) * 64;
          vf[f * 2] = *reinterpret_cast<const bf16x8*>(&Vc[rb + ca]);
          vf[f * 2 + 1] = *reinterpret_cast<const bf16x8*>(&Vc[rb + cb]);
        }
        const bool maskT = (kt >= nkt - 2);
        float xs[4][4];
        float mx4 = -__builtin_inff();
#pragma unroll
        for (int r = 0; r < 4; ++r) {
          const int qg = qrow0 + g * 4 + r;
          xs[r][0] = s4[0][r] * 0.125f;
          xs[r][1] = s4[1][r] * 0.125f;
          xs[r][2] = s4[2][r] * 0.125f;
          xs[r][3] = s4[3][r] * 0.125f;
          if (maskT) {
            if (key0 + c > qg) xs[r][0] = -__builtin_inff();
            if (key0 + 16 + c > qg) xs[r][1] = -__builtin_inff();
            if (key0 + 32 + c > qg) xs[r][2] = -__builtin_inff();
            if (key0 + 48 + c > qg) xs[r][3] = -__builtin_inff();
          }
          const float a0 = fmaxf(xs[r][0], xs[r][1]);
          const float a1 = fmaxf(xs[r][2], xs[r][3]);
          mx4 = fmaxf(mx4, fmaxf(a0, a1) - m[r]);
        }
        if (!__all(mx4 <= 8.0f)) {
#pragma unroll
          for (int r = 0; r < 4; ++r) {
            float tm = fmaxf(fmaxf(xs[r][0], xs[r][1]), fmaxf(xs[r][2], xs[r][3]));
            tm = fmaxf(tm, __shfl_xor(tm, 1, 16));
            tm = fmaxf(tm, __shfl_xor(tm, 2, 16));
            tm = fmaxf(tm, __shfl_xor(tm, 4, 16));
            tm = fmaxf(tm, __shfl_xor(tm, 8, 16));
            const float mn = fmaxf(m[r], tm);
            const float scl = __expf(m[r] - mn);
            lsl[r] *= scl;
            m[r] = mn;
            o[0][r] *= scl;
            o[1][r] *= scl;
            o[2][r] *= scl;
            o[3][r] *= scl;
          }
        }
#pragma unroll
        for (int r = 0; r < 4; ++r) {
          const float p0 = __expf(xs[r][0] - m[r]), p1 = __expf(xs[r][1] - m[r]);
          const float p2 = __expf(xs[r][2] - m[r]), p3 = __expf(xs[r][3] - m[r]);
          lsl[r] += (p0 + p1) + (p2 + p3);
          const int pr = g * 4 + r;
          Plds[w][pr][c] = f2bf(p0);
          Plds[w][pr][c + 16] = f2bf(p1);
          Plds[w][pr][c + 32] = f2bf(p2);
          Plds[w][pr][c + 48] = f2bf(p3);
        }
        asm volatile("" ::: "memory");
        const bf16x8 pa0 = *reinterpret_cast<const bf16x8*>(&Plds[w][c][g * 8]);
        const bf16x8 pa1 = *reinterpret_cast<const bf16x8*>(&Plds[w][c][32 + g * 8]);
        __builtin_amdgcn_s_setprio(1);
#pragma unroll
        for (int f = 0; f < 4; ++f) {
          o[f] = MFMA16(pa0, vf[f * 2], o[f]);
          o[f] = MFMA16(pa1, vf[f * 2 + 1], o[f]);
        }
        __builtin_amdgcn_s_setprio(0);
      }
      __syncthreads();
      cur ^= 1;
    }

    u16* op = O + (size_t)(b * 2048 + qrow0 + g * 4) * 1024 + h * 64 + c;
#pragma unroll
    for (int r = 0; r < 4; ++r) {
      float ls = lsl[r];
      ls += __shfl_xor(ls, 1, 16);
      ls += __shfl_xor(ls, 2, 16);
      ls += __shfl_xor(ls, 4, 16);
      ls += __shfl_xor(ls, 8, 16);
      const float inv = 1.0f / ls;
#pragma unroll
      for (int f = 0; f < 4; ++f) op[(size_t)r * 1024 + f * 16] = f2bf(o[f][r] * inv);
    }
  }
}

// ---------------- launcher ----------------
extern "C" void kernel_launch(void* const* d_in, const int* in_sizes, int n_in,
                              void* d_out, int out_size, void* d_ws, size_t ws_size,
                              hipStream_t stream) {
  const float* H   = (const float*)d_in[0];
  const float* Wq  = (const float*)d_in[1];
  const float* Wk  = (const float*)d_in[2];
  const float* Wv  = (const float*)d_in[3];
  const float* Wo  = (const float*)d_in[4];
  const float* g1  = (const float*)d_in[5];
  const float* be1 = (const float*)d_in[6];
  const float* g2  = (const float*)d_in[7];
  const float* be2 = (const float*)d_in[8];
  const float* W1  = (const float*)d_in[9];
  const float* bb1 = (const float*)d_in[10];
  const float* W2  = (const float*)d_in[11];
  const float* bb2 = (const float*)d_in[12];
  float* out = (float*)d_out;

  if (ws_size < (size_t)67108864) return;  // need 64 MiB
  char* ws = (char*)d_ws;
  u16* Wqkvt = (u16*)(ws + 0);
  u16* Xattn = (u16*)(ws + 6291456);
  u16* QKV   = (u16*)(ws + 14680064);
  u16* Vt    = (u16*)(ws + 39845888);
  u16* Wot   = (u16*)(ws + 48234496);
  u16* W1t   = (u16*)(ws + 50331648);
  u16* W2t   = (u16*)(ws + 58720256);
  u16* Hmlp  = (u16*)(ws + 0);
  u16* Xln2  = Vt;
  u16* Pp    = (u16*)(ws + 39845888);

  wconv12_k<<<dim3(32, 32, 12), dim3(32, 8), 0, stream>>>(Wq, Wk, Wv, Wo, W1, W2,
                                                          Wqkvt, Wot, W1t, W2t);
  ln_k<<<4096, 256, 0, stream>>>(H, g1, be1, Xattn);
  gemm_qkv<<<512, 512, 0, stream>>>(Xattn, Wqkvt, QKV, Vt, 4096, 3072, 1024);
  attn_k<<<dim3(8, 32), 512, 0, stream>>>(QKV, Vt, Xattn);
  gemm_bt64<2><<<256, 256, 0, stream>>>(Xattn, Wot, nullptr, out, nullptr, H,
                                        4096, 1024, 1024, 0);
  ln_k<<<4096, 256, 0, stream>>>(out, g2, be2, Xln2);
  gemm_wide<1><<<512, 512, 0, stream>>>(Xln2, W1t, Hmlp, bb1, 4096, 4096, 1024);
  gemm_bt64<0><<<512, 256, 0, stream>>>(Hmlp, W2t, Pp, nullptr, nullptr, nullptr,
                                        4096, 1024, 4096, 1);
  reduce_k<<<2048, 256, 0, stream>>>(out, Pp, Pp + (size_t)4096 * 1024, bb2);
}

// Round 23
// 226.099 us; speedup vs baseline: 1.1229x; 1.0378x over previous
//
#include <hip/hip_runtime.h>
#include <hip/hip_bf16.h>
#include <math.h>

typedef unsigned short u16;
typedef __bf16 bf16x8 __attribute__((ext_vector_type(8)));
typedef float f32x4 __attribute__((ext_vector_type(4)));
typedef u16 u16x8 __attribute__((ext_vector_type(8)));

#define MFMA16(a, b, c) __builtin_amdgcn_mfma_f32_16x16x32_bf16((a), (b), (c), 0, 0, 0)

__device__ __forceinline__ u16 f2bf(float f) {
  unsigned u = __float_as_uint(f);
  u += 0x7fffu + ((u >> 16) & 1u);
  return (u16)(u >> 16);
}
__device__ __forceinline__ float bf2f(u16 u) {
  return __uint_as_float((unsigned)u << 16);
}

__device__ __forceinline__ void glds16(const u16* g, u16* l) {
  __builtin_amdgcn_global_load_lds((__attribute__((address_space(1))) const void*)g,
                                   (__attribute__((address_space(3))) void*)l, 16, 0, 0);
}

// ---------------- LayerNorm: fp32 [rows][1024] -> bf16 [rows][1024] ----------------
__global__ __launch_bounds__(256) void ln_k(const float* __restrict__ X,
                                            const float* __restrict__ G,
                                            const float* __restrict__ Bv,
                                            u16* __restrict__ out) {
  const int row = blockIdx.x;
  const int t = threadIdx.x;
  const float4 v = reinterpret_cast<const float4*>(X + (size_t)row * 1024)[t];
  float s = v.x + v.y + v.z + v.w;
  float q = v.x * v.x + v.y * v.y + v.z * v.z + v.w * v.w;
  for (int off = 32; off > 0; off >>= 1) {
    s += __shfl_down(s, off);
    q += __shfl_down(q, off);
  }
  __shared__ float ss[4], qs[4];
  const int w = t >> 6, l = t & 63;
  if (l == 0) { ss[w] = s; qs[w] = q; }
  __syncthreads();
  s = ss[0] + ss[1] + ss[2] + ss[3];
  q = qs[0] + qs[1] + qs[2] + qs[3];
  const float mu = s * (1.0f / 1024.0f);
  const float rs = rsqrtf(q * (1.0f / 1024.0f) - mu * mu + 1e-5f);
  const float4 gv = reinterpret_cast<const float4*>(G)[t];
  const float4 bv = reinterpret_cast<const float4*>(Bv)[t];
  union { u16 u[4]; unsigned long long ll; } pk;
  pk.u[0] = f2bf((v.x - mu) * rs * gv.x + bv.x);
  pk.u[1] = f2bf((v.y - mu) * rs * gv.y + bv.y);
  pk.u[2] = f2bf((v.z - mu) * rs * gv.z + bv.z);
  pk.u[3] = f2bf((v.w - mu) * rs * gv.w + bv.w);
  *reinterpret_cast<unsigned long long*>(out + (size_t)row * 1024 + t * 4) = pk.ll;
}

// ---- merged weight convert+transpose: 12 z-slices of 32x32-block transposes ----
__global__ __launch_bounds__(256) void wconv12_k(const float* __restrict__ Wq,
                                                 const float* __restrict__ Wk,
                                                 const float* __restrict__ Wv,
                                                 const float* __restrict__ Wo,
                                                 const float* __restrict__ W1,
                                                 const float* __restrict__ W2,
                                                 u16* __restrict__ Wqkvt,
                                                 u16* __restrict__ Wot,
                                                 u16* __restrict__ W1t,
                                                 u16* __restrict__ W2t) {
  __shared__ u16 tile[32][33];
  const int z = blockIdx.z;
  const float* W;
  u16* Wt;
  int K, N, n0, k0;
  if (z < 4) {
    W = (z == 0) ? Wq : (z == 1) ? Wk : (z == 2) ? Wv : Wo;
    Wt = (z == 3) ? Wot : (Wqkvt + (size_t)z * 1024 * 1024);
    K = 1024; N = 1024;
    n0 = blockIdx.x * 32; k0 = blockIdx.y * 32;
  } else if (z < 8) {
    W = W1; Wt = W1t; K = 1024; N = 4096;
    n0 = blockIdx.x * 32 + (z - 4) * 1024; k0 = blockIdx.y * 32;
  } else {
    W = W2; Wt = W2t; K = 4096; N = 1024;
    n0 = blockIdx.x * 32; k0 = blockIdx.y * 32 + (z - 8) * 1024;
  }
  const int x = threadIdx.x, y = threadIdx.y;
#pragma unroll
  for (int i = 0; i < 4; ++i)
    tile[y + i * 8][x] = f2bf(W[(size_t)(k0 + y + i * 8) * N + n0 + x]);
  __syncthreads();
#pragma unroll
  for (int i = 0; i < 4; ++i)
    Wt[(size_t)(n0 + y + i * 8) * K + k0 + x] = tile[x][y + i * 8];
}

// ------- GEMM 128x128, BK=64 single-buffer (split-K core; kzSplit: 2 halves) --------
template <int EPI>
__global__ __launch_bounds__(256) void gemm_bt64(const u16* __restrict__ A,
                                                 const u16* __restrict__ Bt,
                                                 u16* __restrict__ Cb, float* Cf,
                                                 const float* __restrict__ bias,
                                                 const float* res, int M, int N,
                                                 int K, int kzSplit) {
  __shared__ __align__(16) u16 As[8192];   // [128][64]
  __shared__ __align__(16) u16 Bs[8192];
  const int t = threadIdx.x;
  const int l = t & 63, w = t >> 6;
  const int nbx = N >> 7;
  const int id = blockIdx.x;
  int tiles, tid, kz;
  if (kzSplit) {  // grid = 2 * tiles; kz = id >> 8 (tiles == 256)
    kz = id >> 8;
    tid = id & 255;
    tiles = 256;
  } else {
    kz = 0;
    tid = id;
    tiles = (int)gridDim.x;
  }
  const int qd = tiles >> 3;
  const int swz = (tid & 7) * qd + (tid >> 3);  // XCD swizzle (tiles % 8 == 0)
  const int by = swz / nbx, bx = swz - by * nbx;
  const int Keff = kzSplit ? (K >> 1) : K;
  const int koff = kz * Keff;

  const int scol = ((t & 7) ^ ((t >> 3) & 7)) * 8;
  const u16* gA = A + (size_t)(by * 128 + (t >> 3)) * K + koff + scol;
  const u16* gB = Bt + (size_t)(bx * 128 + (t >> 3)) * K + koff + scol;
  const size_t r32K = (size_t)32 * K;
  const int dst = t * 8;

  const int wr = w >> 1, wc = w & 1;
  const int arow = (wr * 64 + (l & 15)) * 64;
  const int brow = (wc * 64 + (l & 15)) * 64;
  const int ck0 = ((l >> 4) ^ (l & 7)) * 8;
  const int ck1 = ((4 + (l >> 4)) ^ (l & 7)) * 8;

  const f32x4 fz = {0.f, 0.f, 0.f, 0.f};
  f32x4 acc[4][4];
#pragma unroll
  for (int i = 0; i < 4; ++i)
#pragma unroll
    for (int j = 0; j < 4; ++j) acc[i][j] = fz;

  const int nk = Keff >> 6;
  for (int kk = 0; kk < nk; ++kk) {
    __syncthreads();
#pragma unroll
    for (int i = 0; i < 4; ++i) {
      glds16(gA + i * r32K, As + i * 2048 + dst);
      glds16(gB + i * r32K, Bs + i * 2048 + dst);
    }
    gA += 64;
    gB += 64;
    __syncthreads();
#pragma unroll
    for (int ks = 0; ks < 2; ++ks) {
      const int ck = ks ? ck1 : ck0;
      bf16x8 af[4], bv[4];
#pragma unroll
      for (int i = 0; i < 4; ++i)
        af[i] = *reinterpret_cast<const bf16x8*>(&As[arow + i * 1024 + ck]);
#pragma unroll
      for (int j = 0; j < 4; ++j)
        bv[j] = *reinterpret_cast<const bf16x8*>(&Bs[brow + j * 1024 + ck]);
      __builtin_amdgcn_s_setprio(1);
#pragma unroll
      for (int i = 0; i < 4; ++i)
#pragma unroll
        for (int j = 0; j < 4; ++j) acc[i][j] = MFMA16(af[i], bv[j], acc[i][j]);
      __builtin_amdgcn_s_setprio(0);
    }
  }

  const int r0 = by * 128 + wr * 64 + ((l >> 4) << 2);
  const int c0 = bx * 128 + wc * 64 + (l & 15);
  if (EPI == 0) {
    u16* Cp = Cb + (size_t)kz * M * N;
#pragma unroll
    for (int mi = 0; mi < 4; ++mi)
#pragma unroll
      for (int ni = 0; ni < 4; ++ni) {
        const size_t base = (size_t)(r0 + mi * 16) * N + (c0 + ni * 16);
#pragma unroll
        for (int r = 0; r < 4; ++r) Cp[base + (size_t)r * N] = f2bf(acc[mi][ni][r]);
      }
  } else {
#pragma unroll
    for (int mi = 0; mi < 4; ++mi)
#pragma unroll
      for (int ni = 0; ni < 4; ++ni) {
        const int col = c0 + ni * 16;
        const float bb = bias ? bias[col] : 0.0f;
        const size_t base = (size_t)(r0 + mi * 16) * N + col;
#pragma unroll
        for (int r = 0; r < 4; ++r) {
          const size_t idx = base + (size_t)r * N;
          Cf[idx] = res[idx] + acc[mi][ni][r] + bb;
        }
      }
  }
}

// ------- QKV GEMM 128x192, BK=64, 8 waves (2Mx4N, wave 64x48) ---------------------
__global__ __launch_bounds__(512) void gemm_qkv(const u16* __restrict__ A,
                                                const u16* __restrict__ Bt,
                                                u16* __restrict__ Cb,
                                                u16* __restrict__ Vt,
                                                int M, int N, int K) {
  __shared__ __align__(16) u16 As[8192];    // [128][64]
  __shared__ __align__(16) u16 Bs[12288];   // [192][64]
  const int t = threadIdx.x;
  const int l = t & 63, w = t >> 6;
  const int nbx = 16;  // N/192
  const int qd = (int)gridDim.x >> 3;
  const int id = blockIdx.x;
  const int swz = (id & 7) * qd + (id >> 3);  // XCD swizzle (grid % 8 == 0)
  const int by = swz / nbx, bx = swz - by * nbx;

  const int scol = ((t & 7) ^ ((t >> 3) & 7)) * 8;
  const u16* gA = A + (size_t)(by * 128 + (t >> 3)) * K + scol;
  const u16* gB = Bt + (size_t)(bx * 192 + (t >> 3)) * K + scol;
  const size_t r64K = (size_t)64 * K;
  const int dst = t * 8;

  const int wr = w >> 2, wc = w & 3;  // 2M x 4N; wave out 64x48
  const int arow = (wr * 64 + (l & 15)) * 64;
  const int brow = (wc * 48 + (l & 15)) * 64;
  const int ck0 = ((l >> 4) ^ (l & 7)) * 8;
  const int ck1 = ((4 + (l >> 4)) ^ (l & 7)) * 8;

  const f32x4 fz = {0.f, 0.f, 0.f, 0.f};
  f32x4 acc[4][3];
#pragma unroll
  for (int i = 0; i < 4; ++i)
#pragma unroll
    for (int j = 0; j < 3; ++j) acc[i][j] = fz;

  const int nk = K >> 6;
  for (int kk = 0; kk < nk; ++kk) {
    __syncthreads();
    glds16(gA, As + dst);
    glds16(gA + r64K, As + 4096 + dst);
    glds16(gB, Bs + dst);
    glds16(gB + r64K, Bs + 4096 + dst);
    glds16(gB + 2 * r64K, Bs + 8192 + dst);
    gA += 64;
    gB += 64;
    __syncthreads();
#pragma unroll
    for (int ks = 0; ks < 2; ++ks) {
      const int ck = ks ? ck1 : ck0;
      bf16x8 af[4], bv[3];
#pragma unroll
      for (int i = 0; i < 4; ++i)
        af[i] = *reinterpret_cast<const bf16x8*>(&As[arow + i * 1024 + ck]);
#pragma unroll
      for (int j = 0; j < 3; ++j)
        bv[j] = *reinterpret_cast<const bf16x8*>(&Bs[brow + j * 1024 + ck]);
      __builtin_amdgcn_s_setprio(1);
#pragma unroll
      for (int i = 0; i < 4; ++i)
#pragma unroll
        for (int j = 0; j < 3; ++j) acc[i][j] = MFMA16(af[i], bv[j], acc[i][j]);
      __builtin_amdgcn_s_setprio(0);
    }
  }

  const int r0 = by * 128 + wr * 64 + ((l >> 4) << 2);
  const int b = (by * 128) >> 11;  // 2048-row batch (tile never straddles)
#pragma unroll
  for (int mi = 0; mi < 4; ++mi) {
    const int row = r0 + mi * 16;
#pragma unroll
    for (int ni = 0; ni < 3; ++ni) {
      const int colblk = bx * 192 + wc * 48 + ni * 16;  // wave-uniform
      const int col = colblk + (l & 15);
      if (colblk >= 2048) {  // V fragment -> transposed Vt write
        const int h = (col - 2048) >> 6;
        const int dk = (col - 2048) & 63;
        const int tt = row - b * 2048;
        union { u16 u[4]; unsigned long long ll; } pk;
#pragma unroll
        for (int r = 0; r < 4; ++r) pk.u[r] = f2bf(acc[mi][ni][r]);
        *reinterpret_cast<unsigned long long*>(
            &Vt[(((size_t)b * 16 + h) * 64 + dk) * 2048 + tt]) = pk.ll;
      } else {
        const size_t base = (size_t)row * N + col;
#pragma unroll
        for (int r = 0; r < 4; ++r) Cb[base + (size_t)r * N] = f2bf(acc[mi][ni][r]);
      }
    }
  }
}

// ------- GEMM 128x256, BK=64 single-buffer, 8 waves (MLP1) --------------------------
template <int EPI>
__global__ __launch_bounds__(512) void gemm_wide(const u16* __restrict__ A,
                                                 const u16* __restrict__ Bt,
                                                 u16* __restrict__ Cb,
                                                 const float* __restrict__ bias,
                                                 int M, int N, int K) {
  __shared__ __align__(16) u16 As[8192];    // [128][64]
  __shared__ __align__(16) u16 Bs[16384];   // [256][64]
  const int t = threadIdx.x;
  const int l = t & 63, w = t >> 6;
  const int nbx = N >> 8;
  const int qd = (int)gridDim.x >> 3;
  const int id = blockIdx.x;
  const int swz = (id & 7) * qd + (id >> 3);  // XCD swizzle (grid % 8 == 0)
  const int by = swz / nbx, bx = swz - by * nbx;

  const int scol = ((t & 7) ^ ((t >> 3) & 7)) * 8;
  const u16* gA = A + (size_t)(by * 128 + (t >> 3)) * K + scol;
  const u16* gB = Bt + (size_t)(bx * 256 + (t >> 3)) * K + scol;
  const size_t r64K = (size_t)64 * K;
  const int dst = t * 8;

  const int wr = w >> 2, wc = w & 3;  // 2M x 4N; wave out 64x64
  const int arow = (wr * 64 + (l & 15)) * 64;
  const int brow = (wc * 64 + (l & 15)) * 64;
  const int ck0 = ((l >> 4) ^ (l & 7)) * 8;
  const int ck1 = ((4 + (l >> 4)) ^ (l & 7)) * 8;

  const f32x4 fz = {0.f, 0.f, 0.f, 0.f};
  f32x4 acc[4][4];
#pragma unroll
  for (int i = 0; i < 4; ++i)
#pragma unroll
    for (int j = 0; j < 4; ++j) acc[i][j] = fz;

  const int nk = K >> 6;
  for (int kk = 0; kk < nk; ++kk) {
    __syncthreads();
    glds16(gA, As + dst);
    glds16(gA + r64K, As + 4096 + dst);
    glds16(gB, Bs + dst);
    glds16(gB + r64K, Bs + 4096 + dst);
    glds16(gB + 2 * r64K, Bs + 8192 + dst);
    glds16(gB + 3 * r64K, Bs + 12288 + dst);
    gA += 64;
    gB += 64;
    __syncthreads();
#pragma unroll
    for (int ks = 0; ks < 2; ++ks) {
      const int ck = ks ? ck1 : ck0;
      bf16x8 af[4], bv[4];
#pragma unroll
      for (int i = 0; i < 4; ++i)
        af[i] = *reinterpret_cast<const bf16x8*>(&As[arow + i * 1024 + ck]);
#pragma unroll
      for (int j = 0; j < 4; ++j)
        bv[j] = *reinterpret_cast<const bf16x8*>(&Bs[brow + j * 1024 + ck]);
      __builtin_amdgcn_s_setprio(1);
#pragma unroll
      for (int i = 0; i < 4; ++i)
#pragma unroll
        for (int j = 0; j < 4; ++j) acc[i][j] = MFMA16(af[i], bv[j], acc[i][j]);
      __builtin_amdgcn_s_setprio(0);
    }
  }

  const int r0 = by * 128 + wr * 64 + ((l >> 4) << 2);
  const int c0 = bx * 256 + wc * 64 + (l & 15);
#pragma unroll
  for (int mi = 0; mi < 4; ++mi)
#pragma unroll
    for (int ni = 0; ni < 4; ++ni) {
      const int col = c0 + ni * 16;
      const size_t base = (size_t)(r0 + mi * 16) * N + col;
      if (EPI == 0) {
#pragma unroll
        for (int r = 0; r < 4; ++r) Cb[base + (size_t)r * N] = f2bf(acc[mi][ni][r]);
      } else {
        const float bb = bias[col];
#pragma unroll
        for (int r = 0; r < 4; ++r) {
          const float x = acc[mi][ni][r] + bb;
          const float gl = 0.5f * x * (1.0f + erff(x * 0.70710678118654752f));
          Cb[base + (size_t)r * N] = f2bf(gl);
        }
      }
    }
}

// ---------------- reduce: out += P0 + P1 + bias  (4096x1024 f32) ----------------
__global__ __launch_bounds__(256) void reduce_k(float* __restrict__ out,
                                                const u16* __restrict__ P0,
                                                const u16* __restrict__ P1,
                                                const float* __restrict__ bias) {
  const int q0 = blockIdx.x * 256 + threadIdx.x;
#pragma unroll
  for (int it = 0; it < 2; ++it) {
    const size_t q = ((size_t)q0 + (size_t)it * 524288) * 4;
    float4 o = *reinterpret_cast<float4*>(&out[q]);
    const ushort4 a = *reinterpret_cast<const ushort4*>(&P0[q]);
    const ushort4 b = *reinterpret_cast<const ushort4*>(&P1[q]);
    const float4 bb = *reinterpret_cast<const float4*>(&bias[q & 1023]);
    o.x += bf2f(a.x) + bf2f(b.x) + bb.x;
    o.y += bf2f(a.y) + bf2f(b.y) + bb.y;
    o.z += bf2f(a.z) + bf2f(b.z) + bb.z;
    o.w += bf2f(a.w) + bf2f(b.w) + bb.w;
    *reinterpret_cast<float4*>(&out[q]) = o;
  }
}

// ---------------- reduceH: out = H + P0 + P1  (proj split-K merge) ----------------
__global__ __launch_bounds__(256) void reduceH_k(float* __restrict__ out,
                                                 const float* __restrict__ H,
                                                 const u16* __restrict__ P0,
                                                 const u16* __restrict__ P1) {
  const int q0 = blockIdx.x * 256 + threadIdx.x;
#pragma unroll
  for (int it = 0; it < 2; ++it) {
    const size_t q = ((size_t)q0 + (size_t)it * 524288) * 4;
    const float4 hv = *reinterpret_cast<const float4*>(&H[q]);
    const ushort4 a = *reinterpret_cast<const ushort4*>(&P0[q]);
    const ushort4 b = *reinterpret_cast<const ushort4*>(&P1[q]);
    float4 o;
    o.x = hv.x + bf2f(a.x) + bf2f(b.x);
    o.y = hv.y + bf2f(a.y) + bf2f(b.y);
    o.z = hv.z + bf2f(a.z) + bf2f(b.z);
    o.w = hv.w + bf2f(a.w) + bf2f(b.w);
    *reinterpret_cast<float4*>(&out[q]) = o;
  }
}

// ---------------- causal flash attention (LDS-staged K/V, 8 waves, 128-row qblk) ----
__global__ __launch_bounds__(512) void attn_k(const u16* __restrict__ QKV,
                                              const u16* __restrict__ Vt,
                                              u16* __restrict__ O) {
  __shared__ __align__(16) u16 Kbuf[2][4096];
  __shared__ __align__(16) u16 Vbuf[2][4096];
  __shared__ __align__(16) u16 Plds[8][16][68];
  const int t = threadIdx.x;
  const int l = t & 63, w = t >> 6;
  const int g = l >> 4, c = l & 15;
  const int pj = blockIdx.x, bh = blockIdx.y;
  const int b = bh >> 4, h = bh & 15;
  const u16* Kp = QKV + (size_t)b * 2048 * 3072 + 1024 + h * 64;
  const u16* Vp = Vt + (size_t)bh * 64 * 2048;
  const f32x4 fz = {0.f, 0.f, 0.f, 0.f};
  const int srow = t >> 3;
  const int scol = ((t & 7) ^ (srow & 7)) * 8;
  u16* kdst0 = &Kbuf[0][w * 512];
  u16* kdst1 = &Kbuf[1][w * 512];
  u16* vdst0 = &Vbuf[0][w * 512];
  u16* vdst1 = &Vbuf[1][w * 512];
  const int ca = (g ^ (c & 7)) * 8;
  const int cb = ((g + 4) ^ (c & 7)) * 8;

#pragma unroll 1
  for (int hf = 0; hf < 2; ++hf) {
    const int qblk = hf ? (15 - pj) : pj;
    const int nkt = 2 * qblk + 2;
    const int qrow0 = qblk * 128 + w * 16;
    const size_t qoff = (size_t)(b * 2048 + qrow0 + c) * 3072 + h * 64 + g * 8;
    const bf16x8 qf0 = *reinterpret_cast<const bf16x8*>(&QKV[qoff]);
    const bf16x8 qf1 = *reinterpret_cast<const bf16x8*>(&QKV[qoff + 32]);
    f32x4 o[4];
    float m[4], lsl[4];
#pragma unroll
    for (int f = 0; f < 4; ++f) o[f] = fz;
#pragma unroll
    for (int r = 0; r < 4; ++r) {
      m[r] = -__builtin_inff();
      lsl[r] = 0.f;
    }
    glds16(Kp + (size_t)srow * 3072 + scol, kdst0);
    glds16(Vp + (size_t)srow * 2048 + scol, vdst0);
    __syncthreads();
    int cur = 0;

#pragma unroll 1
    for (int kt = 0; kt < nkt; ++kt) {
      const int key0 = kt * 64;
      if (kt + 1 < nkt) {
        const int kn = key0 + 64;
        glds16(Kp + (size_t)(kn + srow) * 3072 + scol, cur ? kdst0 : kdst1);
        glds16(Vp + (size_t)srow * 2048 + kn + scol, cur ? vdst0 : vdst1);
      }
      if (key0 <= qrow0 + 15) {
        const u16* Kc = Kbuf[cur];
        const u16* Vc = Vbuf[cur];
        f32x4 s4[4];
        __builtin_amdgcn_s_setprio(1);
#pragma unroll
        for (int kq = 0; kq < 4; ++kq) {
          const int rb = (c + 16 * kq) * 64;
          const bf16x8 k0 = *reinterpret_cast<const bf16x8*>(&Kc[rb + ca]);
          const bf16x8 k1 = *reinterpret_cast<const bf16x8*>(&Kc[rb + cb]);
          s4[kq] = MFMA16(qf0, k0, fz);
          s4[kq] = MFMA16(qf1, k1, s4[kq]);
        }
        __builtin_amdgcn_s_setprio(0);
        bf16x8 vf[8];
#pragma unroll
        for (int f = 0; f < 4; ++f) {
          const int rb = (c + 16 * f) * 64;
          vf[f * 2] = *reinterpret_cast<const bf16x8*>(&Vc[rb + ca]);
          vf[f * 2 + 1] = *reinterpret_cast<const bf16x8*>(&Vc[rb + cb]);
        }
        const bool maskT = (kt >= nkt - 2);
        float xs[4][4];
        float mx4 = -__builtin_inff();
#pragma unroll
        for (int r = 0; r < 4; ++r) {
          const int qg = qrow0 + g * 4 + r;
          xs[r][0] = s4[0][r] * 0.125f;
          xs[r][1] = s4[1][r] * 0.125f;
          xs[r][2] = s4[2][r] * 0.125f;
          xs[r][3] = s4[3][r] * 0.125f;
          if (maskT) {
            if (key0 + c > qg) xs[r][0] = -__builtin_inff();
            if (key0 + 16 + c > qg) xs[r][1] = -__builtin_inff();
            if (key0 + 32 + c > qg) xs[r][2] = -__builtin_inff();
            if (key0 + 48 + c > qg) xs[r][3] = -__builtin_inff();
          }
          const float a0 = fmaxf(xs[r][0], xs[r][1]);
          const float a1 = fmaxf(xs[r][2], xs[r][3]);
          mx4 = fmaxf(mx4, fmaxf(a0, a1) - m[r]);
        }
        if (!__all(mx4 <= 8.0f)) {
#pragma unroll
          for (int r = 0; r < 4; ++r) {
            float tm = fmaxf(fmaxf(xs[r][0], xs[r][1]), fmaxf(xs[r][2], xs[r][3]));
            tm = fmaxf(tm, __shfl_xor(tm, 1, 16));
            tm = fmaxf(tm, __shfl_xor(tm, 2, 16));
            tm = fmaxf(tm, __shfl_xor(tm, 4, 16));
            tm = fmaxf(tm, __shfl_xor(tm, 8, 16));
            const float mn = fmaxf(m[r], tm);
            const float scl = __expf(m[r] - mn);
            lsl[r] *= scl;
            m[r] = mn;
            o[0][r] *= scl;
            o[1][r] *= scl;
            o[2][r] *= scl;
            o[3][r] *= scl;
          }
        }
#pragma unroll
        for (int r = 0; r < 4; ++r) {
          const float p0 = __expf(xs[r][0] - m[r]), p1 = __expf(xs[r][1] - m[r]);
          const float p2 = __expf(xs[r][2] - m[r]), p3 = __expf(xs[r][3] - m[r]);
          lsl[r] += (p0 + p1) + (p2 + p3);
          const int pr = g * 4 + r;
          Plds[w][pr][c] = f2bf(p0);
          Plds[w][pr][c + 16] = f2bf(p1);
          Plds[w][pr][c + 32] = f2bf(p2);
          Plds[w][pr][c + 48] = f2bf(p3);
        }
        asm volatile("" ::: "memory");
        const bf16x8 pa0 = *reinterpret_cast<const bf16x8*>(&Plds[w][c][g * 8]);
        const bf16x8 pa1 = *reinterpret_cast<const bf16x8*>(&Plds[w][c][32 + g * 8]);
        __builtin_amdgcn_s_setprio(1);
#pragma unroll
        for (int f = 0; f < 4; ++f) {
          o[f] = MFMA16(pa0, vf[f * 2], o[f]);
          o[f] = MFMA16(pa1, vf[f * 2 + 1], o[f]);
        }
        __builtin_amdgcn_s_setprio(0);
      }
      __syncthreads();
      cur ^= 1;
    }

    u16* op = O + (size_t)(b * 2048 + qrow0 + g * 4) * 1024 + h * 64 + c;
#pragma unroll
    for (int r = 0; r < 4; ++r) {
      float ls = lsl[r];
      ls += __shfl_xor(ls, 1, 16);
      ls += __shfl_xor(ls, 2, 16);
      ls += __shfl_xor(ls, 4, 16);
      ls += __shfl_xor(ls, 8, 16);
      const float inv = 1.0f / ls;
#pragma unroll
      for (int f = 0; f < 4; ++f) op[(size_t)r * 1024 + f * 16] = f2bf(o[f][r] * inv);
    }
  }
}

// ---------------- launcher ----------------
extern "C" void kernel_launch(void* const* d_in, const int* in_sizes, int n_in,
                              void* d_out, int out_size, void* d_ws, size_t ws_size,
                              hipStream_t stream) {
  const float* H   = (const float*)d_in[0];
  const float* Wq  = (const float*)d_in[1];
  const float* Wk  = (const float*)d_in[2];
  const float* Wv  = (const float*)d_in[3];
  const float* Wo  = (const float*)d_in[4];
  const float* g1  = (const float*)d_in[5];
  const float* be1 = (const float*)d_in[6];
  const float* g2  = (const float*)d_in[7];
  const float* be2 = (const float*)d_in[8];
  const float* W1  = (const float*)d_in[9];
  const float* bb1 = (const float*)d_in[10];
  const float* W2  = (const float*)d_in[11];
  const float* bb2 = (const float*)d_in[12];
  float* out = (float*)d_out;

  if (ws_size < (size_t)67108864) return;  // need 64 MiB
  char* ws = (char*)d_ws;
  u16* Wqkvt  = (u16*)(ws + 0);         //  6.29MB  dead after QKV gemm
  u16* Xattn  = (u16*)(ws + 6291456);   //  8.39MB  ln1 out -> attn out -> proj input
  u16* QKV    = (u16*)(ws + 14680064);  // 25.17MB  dead after attn
  u16* Vt     = (u16*)(ws + 39845888);  //  8.39MB  dead after attn; later Xln2
  u16* Wot    = (u16*)(ws + 48234496);  //  2.10MB  live until proj done
  u16* W1t    = (u16*)(ws + 50331648);  //  8.39MB  live until MLP1 done
  u16* W2t    = (u16*)(ws + 58720256);  //  8.39MB  live until MLP2 done
  u16* Hmlp   = (u16*)(ws + 0);         // 33.55MB  overlay (after proj+reduceH)
  u16* Xln2   = Vt;
  u16* PpProj = (u16*)(ws + 14680064);  // 16.78MB  proj partials (QKV region, dead;
                                        //          consumed by reduceH before Hmlp)
  u16* Pp     = (u16*)(ws + 39845888);  // 16.78MB  MLP2 partials (Vt/Wot/W1t dead then)

  wconv12_k<<<dim3(32, 32, 12), dim3(32, 8), 0, stream>>>(Wq, Wk, Wv, Wo, W1, W2,
                                                          Wqkvt, Wot, W1t, W2t);
  ln_k<<<4096, 256, 0, stream>>>(H, g1, be1, Xattn);
  gemm_qkv<<<512, 512, 0, stream>>>(Xattn, Wqkvt, QKV, Vt, 4096, 3072, 1024);
  attn_k<<<dim3(8, 32), 512, 0, stream>>>(QKV, Vt, Xattn);
  // proj split-K=2: partials into PpProj (QKV region; Wot/W1t untouched)
  gemm_bt64<0><<<512, 256, 0, stream>>>(Xattn, Wot, PpProj, nullptr, nullptr, nullptr,
                                        4096, 1024, 1024, 1);
  reduceH_k<<<2048, 256, 0, stream>>>(out, H, PpProj, PpProj + (size_t)4096 * 1024);
  ln_k<<<4096, 256, 0, stream>>>(out, g2, be2, Xln2);
  gemm_wide<1><<<512, 512, 0, stream>>>(Xln2, W1t, Hmlp, bb1, 4096, 4096, 1024);
  gemm_bt64<0><<<512, 256, 0, stream>>>(Hmlp, W2t, Pp, nullptr, nullptr, nullptr,
                                        4096, 1024, 4096, 1);
  reduce_k<<<2048, 256, 0, stream>>>(out, Pp, Pp + (size_t)4096 * 1024, bb2);
}

// Round 24
// 221.089 us; speedup vs baseline: 1.1483x; 1.0227x over previous
//
#include <hip/hip_runtime.h>
#include <hip/hip_bf16.h>
#include <math.h>

typedef unsigned short u16;
typedef __bf16 bf16x8 __attribute__((ext_vector_type(8)));
typedef float f32x4 __attribute__((ext_vector_type(4)));
typedef u16 u16x8 __attribute__((ext_vector_type(8)));

#define MFMA16(a, b, c) __builtin_amdgcn_mfma_f32_16x16x32_bf16((a), (b), (c), 0, 0, 0)

__device__ __forceinline__ u16 f2bf(float f) {
  unsigned u = __float_as_uint(f);
  u += 0x7fffu + ((u >> 16) & 1u);
  return (u16)(u >> 16);
}
__device__ __forceinline__ float bf2f(u16 u) {
  return __uint_as_float((unsigned)u << 16);
}

__device__ __forceinline__ void glds16(const u16* g, u16* l) {
  __builtin_amdgcn_global_load_lds((__attribute__((address_space(1))) const void*)g,
                                   (__attribute__((address_space(3))) void*)l, 16, 0, 0);
}

// ---------------- LayerNorm: fp32 [rows][1024] -> bf16 [rows][1024] ----------------
__global__ __launch_bounds__(256) void ln_k(const float* __restrict__ X,
                                            const float* __restrict__ G,
                                            const float* __restrict__ Bv,
                                            u16* __restrict__ out) {
  const int row = blockIdx.x;
  const int t = threadIdx.x;
  const float4 v = reinterpret_cast<const float4*>(X + (size_t)row * 1024)[t];
  float s = v.x + v.y + v.z + v.w;
  float q = v.x * v.x + v.y * v.y + v.z * v.z + v.w * v.w;
  for (int off = 32; off > 0; off >>= 1) {
    s += __shfl_down(s, off);
    q += __shfl_down(q, off);
  }
  __shared__ float ss[4], qs[4];
  const int w = t >> 6, l = t & 63;
  if (l == 0) { ss[w] = s; qs[w] = q; }
  __syncthreads();
  s = ss[0] + ss[1] + ss[2] + ss[3];
  q = qs[0] + qs[1] + qs[2] + qs[3];
  const float mu = s * (1.0f / 1024.0f);
  const float rs = rsqrtf(q * (1.0f / 1024.0f) - mu * mu + 1e-5f);
  const float4 gv = reinterpret_cast<const float4*>(G)[t];
  const float4 bv = reinterpret_cast<const float4*>(Bv)[t];
  union { u16 u[4]; unsigned long long ll; } pk;
  pk.u[0] = f2bf((v.x - mu) * rs * gv.x + bv.x);
  pk.u[1] = f2bf((v.y - mu) * rs * gv.y + bv.y);
  pk.u[2] = f2bf((v.z - mu) * rs * gv.z + bv.z);
  pk.u[3] = f2bf((v.w - mu) * rs * gv.w + bv.w);
  *reinterpret_cast<unsigned long long*>(out + (size_t)row * 1024 + t * 4) = pk.ll;
}

// ---- fused proj-split merge + LayerNorm: out = H+P0+P1 (fp32); Xln2 = LN(out) ----
__global__ __launch_bounds__(256) void lnres_k(float* __restrict__ out,
                                               const float* __restrict__ H,
                                               const u16* __restrict__ P0,
                                               const u16* __restrict__ P1,
                                               const float* __restrict__ G,
                                               const float* __restrict__ Bv,
                                               u16* __restrict__ xout) {
  const int row = blockIdx.x;
  const int t = threadIdx.x;
  const size_t q4 = (size_t)row * 256 + t;
  const float4 hv = reinterpret_cast<const float4*>(H)[q4];
  const ushort4 a = reinterpret_cast<const ushort4*>(P0)[q4];
  const ushort4 b = reinterpret_cast<const ushort4*>(P1)[q4];
  float4 v;
  v.x = hv.x + bf2f(a.x) + bf2f(b.x);
  v.y = hv.y + bf2f(a.y) + bf2f(b.y);
  v.z = hv.z + bf2f(a.z) + bf2f(b.z);
  v.w = hv.w + bf2f(a.w) + bf2f(b.w);
  reinterpret_cast<float4*>(out)[q4] = v;
  float s = v.x + v.y + v.z + v.w;
  float q = v.x * v.x + v.y * v.y + v.z * v.z + v.w * v.w;
  for (int off = 32; off > 0; off >>= 1) {
    s += __shfl_down(s, off);
    q += __shfl_down(q, off);
  }
  __shared__ float ss[4], qs[4];
  const int w = t >> 6, l = t & 63;
  if (l == 0) { ss[w] = s; qs[w] = q; }
  __syncthreads();
  s = ss[0] + ss[1] + ss[2] + ss[3];
  q = qs[0] + qs[1] + qs[2] + qs[3];
  const float mu = s * (1.0f / 1024.0f);
  const float rs = rsqrtf(q * (1.0f / 1024.0f) - mu * mu + 1e-5f);
  const float4 gv = reinterpret_cast<const float4*>(G)[t];
  const float4 bv = reinterpret_cast<const float4*>(Bv)[t];
  union { u16 u[4]; unsigned long long ll; } pk;
  pk.u[0] = f2bf((v.x - mu) * rs * gv.x + bv.x);
  pk.u[1] = f2bf((v.y - mu) * rs * gv.y + bv.y);
  pk.u[2] = f2bf((v.z - mu) * rs * gv.z + bv.z);
  pk.u[3] = f2bf((v.w - mu) * rs * gv.w + bv.w);
  *reinterpret_cast<unsigned long long*>(xout + (size_t)row * 1024 + t * 4) = pk.ll;
}

// ---- merged weight convert+transpose: 12 z-slices of 32x32-block transposes ----
__global__ __launch_bounds__(256) void wconv12_k(const float* __restrict__ Wq,
                                                 const float* __restrict__ Wk,
                                                 const float* __restrict__ Wv,
                                                 const float* __restrict__ Wo,
                                                 const float* __restrict__ W1,
                                                 const float* __restrict__ W2,
                                                 u16* __restrict__ Wqkvt,
                                                 u16* __restrict__ Wot,
                                                 u16* __restrict__ W1t,
                                                 u16* __restrict__ W2t) {
  __shared__ u16 tile[32][33];
  const int z = blockIdx.z;
  const float* W;
  u16* Wt;
  int K, N, n0, k0;
  if (z < 4) {
    W = (z == 0) ? Wq : (z == 1) ? Wk : (z == 2) ? Wv : Wo;
    Wt = (z == 3) ? Wot : (Wqkvt + (size_t)z * 1024 * 1024);
    K = 1024; N = 1024;
    n0 = blockIdx.x * 32; k0 = blockIdx.y * 32;
  } else if (z < 8) {
    W = W1; Wt = W1t; K = 1024; N = 4096;
    n0 = blockIdx.x * 32 + (z - 4) * 1024; k0 = blockIdx.y * 32;
  } else {
    W = W2; Wt = W2t; K = 4096; N = 1024;
    n0 = blockIdx.x * 32; k0 = blockIdx.y * 32 + (z - 8) * 1024;
  }
  const int x = threadIdx.x, y = threadIdx.y;
#pragma unroll
  for (int i = 0; i < 4; ++i)
    tile[y + i * 8][x] = f2bf(W[(size_t)(k0 + y + i * 8) * N + n0 + x]);
  __syncthreads();
#pragma unroll
  for (int i = 0; i < 4; ++i)
    Wt[(size_t)(n0 + y + i * 8) * K + k0 + x] = tile[x][y + i * 8];
}

// ------- GEMM 128x128, BK=64 single-buffer (split-K core; kzSplit: 2 halves) --------
template <int EPI>
__global__ __launch_bounds__(256) void gemm_bt64(const u16* __restrict__ A,
                                                 const u16* __restrict__ Bt,
                                                 u16* __restrict__ Cb, float* Cf,
                                                 const float* __restrict__ bias,
                                                 const float* res, int M, int N,
                                                 int K, int kzSplit) {
  __shared__ __align__(16) u16 As[8192];   // [128][64]
  __shared__ __align__(16) u16 Bs[8192];
  const int t = threadIdx.x;
  const int l = t & 63, w = t >> 6;
  const int nbx = N >> 7;
  const int id = blockIdx.x;
  int tiles, tid, kz;
  if (kzSplit) {  // grid = 2 * tiles; kz = id >> 8 (tiles == 256)
    kz = id >> 8;
    tid = id & 255;
    tiles = 256;
  } else {
    kz = 0;
    tid = id;
    tiles = (int)gridDim.x;
  }
  const int qd = tiles >> 3;
  const int swz = (tid & 7) * qd + (tid >> 3);  // XCD swizzle (tiles % 8 == 0)
  const int by = swz / nbx, bx = swz - by * nbx;
  const int Keff = kzSplit ? (K >> 1) : K;
  const int koff = kz * Keff;

  const int scol = ((t & 7) ^ ((t >> 3) & 7)) * 8;
  const u16* gA = A + (size_t)(by * 128 + (t >> 3)) * K + koff + scol;
  const u16* gB = Bt + (size_t)(bx * 128 + (t >> 3)) * K + koff + scol;
  const size_t r32K = (size_t)32 * K;
  const int dst = t * 8;

  const int wr = w >> 1, wc = w & 1;
  const int arow = (wr * 64 + (l & 15)) * 64;
  const int brow = (wc * 64 + (l & 15)) * 64;
  const int ck0 = ((l >> 4) ^ (l & 7)) * 8;
  const int ck1 = ((4 + (l >> 4)) ^ (l & 7)) * 8;

  const f32x4 fz = {0.f, 0.f, 0.f, 0.f};
  f32x4 acc[4][4];
#pragma unroll
  for (int i = 0; i < 4; ++i)
#pragma unroll
    for (int j = 0; j < 4; ++j) acc[i][j] = fz;

  const int nk = Keff >> 6;
  for (int kk = 0; kk < nk; ++kk) {
    __syncthreads();
#pragma unroll
    for (int i = 0; i < 4; ++i) {
      glds16(gA + i * r32K, As + i * 2048 + dst);
      glds16(gB + i * r32K, Bs + i * 2048 + dst);
    }
    gA += 64;
    gB += 64;
    __syncthreads();
#pragma unroll
    for (int ks = 0; ks < 2; ++ks) {
      const int ck = ks ? ck1 : ck0;
      bf16x8 af[4], bv[4];
#pragma unroll
      for (int i = 0; i < 4; ++i)
        af[i] = *reinterpret_cast<const bf16x8*>(&As[arow + i * 1024 + ck]);
#pragma unroll
      for (int j = 0; j < 4; ++j)
        bv[j] = *reinterpret_cast<const bf16x8*>(&Bs[brow + j * 1024 + ck]);
      __builtin_amdgcn_s_setprio(1);
#pragma unroll
      for (int i = 0; i < 4; ++i)
#pragma unroll
        for (int j = 0; j < 4; ++j) acc[i][j] = MFMA16(af[i], bv[j], acc[i][j]);
      __builtin_amdgcn_s_setprio(0);
    }
  }

  const int r0 = by * 128 + wr * 64 + ((l >> 4) << 2);
  const int c0 = bx * 128 + wc * 64 + (l & 15);
  if (EPI == 0) {
    u16* Cp = Cb + (size_t)kz * M * N;
#pragma unroll
    for (int mi = 0; mi < 4; ++mi)
#pragma unroll
      for (int ni = 0; ni < 4; ++ni) {
        const size_t base = (size_t)(r0 + mi * 16) * N + (c0 + ni * 16);
#pragma unroll
        for (int r = 0; r < 4; ++r) Cp[base + (size_t)r * N] = f2bf(acc[mi][ni][r]);
      }
  } else {
#pragma unroll
    for (int mi = 0; mi < 4; ++mi)
#pragma unroll
      for (int ni = 0; ni < 4; ++ni) {
        const int col = c0 + ni * 16;
        const float bb = bias ? bias[col] : 0.0f;
        const size_t base = (size_t)(r0 + mi * 16) * N + col;
#pragma unroll
        for (int r = 0; r < 4; ++r) {
          const size_t idx = base + (size_t)r * N;
          Cf[idx] = res[idx] + acc[mi][ni][r] + bb;
        }
      }
  }
}

// ------- QKV GEMM 128x192, BK=64, 8 waves (2Mx4N, wave 64x48) ---------------------
__global__ __launch_bounds__(512) void gemm_qkv(const u16* __restrict__ A,
                                                const u16* __restrict__ Bt,
                                                u16* __restrict__ Cb,
                                                u16* __restrict__ Vt,
                                                int M, int N, int K) {
  __shared__ __align__(16) u16 As[8192];    // [128][64]
  __shared__ __align__(16) u16 Bs[12288];   // [192][64]
  const int t = threadIdx.x;
  const int l = t & 63, w = t >> 6;
  const int nbx = 16;  // N/192
  const int qd = (int)gridDim.x >> 3;
  const int id = blockIdx.x;
  const int swz = (id & 7) * qd + (id >> 3);  // XCD swizzle (grid % 8 == 0)
  const int by = swz / nbx, bx = swz - by * nbx;

  const int scol = ((t & 7) ^ ((t >> 3) & 7)) * 8;
  const u16* gA = A + (size_t)(by * 128 + (t >> 3)) * K + scol;
  const u16* gB = Bt + (size_t)(bx * 192 + (t >> 3)) * K + scol;
  const size_t r64K = (size_t)64 * K;
  const int dst = t * 8;

  const int wr = w >> 2, wc = w & 3;  // 2M x 4N; wave out 64x48
  const int arow = (wr * 64 + (l & 15)) * 64;
  const int brow = (wc * 48 + (l & 15)) * 64;
  const int ck0 = ((l >> 4) ^ (l & 7)) * 8;
  const int ck1 = ((4 + (l >> 4)) ^ (l & 7)) * 8;

  const f32x4 fz = {0.f, 0.f, 0.f, 0.f};
  f32x4 acc[4][3];
#pragma unroll
  for (int i = 0; i < 4; ++i)
#pragma unroll
    for (int j = 0; j < 3; ++j) acc[i][j] = fz;

  const int nk = K >> 6;
  for (int kk = 0; kk < nk; ++kk) {
    __syncthreads();
    glds16(gA, As + dst);
    glds16(gA + r64K, As + 4096 + dst);
    glds16(gB, Bs + dst);
    glds16(gB + r64K, Bs + 4096 + dst);
    glds16(gB + 2 * r64K, Bs + 8192 + dst);
    gA += 64;
    gB += 64;
    __syncthreads();
#pragma unroll
    for (int ks = 0; ks < 2; ++ks) {
      const int ck = ks ? ck1 : ck0;
      bf16x8 af[4], bv[3];
#pragma unroll
      for (int i = 0; i < 4; ++i)
        af[i] = *reinterpret_cast<const bf16x8*>(&As[arow + i * 1024 + ck]);
#pragma unroll
      for (int j = 0; j < 3; ++j)
        bv[j] = *reinterpret_cast<const bf16x8*>(&Bs[brow + j * 1024 + ck]);
      __builtin_amdgcn_s_setprio(1);
#pragma unroll
      for (int i = 0; i < 4; ++i)
#pragma unroll
        for (int j = 0; j < 3; ++j) acc[i][j] = MFMA16(af[i], bv[j], acc[i][j]);
      __builtin_amdgcn_s_setprio(0);
    }
  }

  const int r0 = by * 128 + wr * 64 + ((l >> 4) << 2);
  const int b = (by * 128) >> 11;  // 2048-row batch (tile never straddles)
#pragma unroll
  for (int mi = 0; mi < 4; ++mi) {
    const int row = r0 + mi * 16;
#pragma unroll
    for (int ni = 0; ni < 3; ++ni) {
      const int colblk = bx * 192 + wc * 48 + ni * 16;  // wave-uniform
      const int col = colblk + (l & 15);
      if (colblk >= 2048) {  // V fragment -> transposed Vt write
        const int h = (col - 2048) >> 6;
        const int dk = (col - 2048) & 63;
        const int tt = row - b * 2048;
        union { u16 u[4]; unsigned long long ll; } pk;
#pragma unroll
        for (int r = 0; r < 4; ++r) pk.u[r] = f2bf(acc[mi][ni][r]);
        *reinterpret_cast<unsigned long long*>(
            &Vt[(((size_t)b * 16 + h) * 64 + dk) * 2048 + tt]) = pk.ll;
      } else {
        const size_t base = (size_t)row * N + col;
#pragma unroll
        for (int r = 0; r < 4; ++r) Cb[base + (size_t)r * N] = f2bf(acc[mi][ni][r]);
      }
    }
  }
}

// ------- GEMM 128x256, BK=64 single-buffer, 8 waves (MLP1) --------------------------
template <int EPI>
__global__ __launch_bounds__(512) void gemm_wide(const u16* __restrict__ A,
                                                 const u16* __restrict__ Bt,
                                                 u16* __restrict__ Cb,
                                                 const float* __restrict__ bias,
                                                 int M, int N, int K) {
  __shared__ __align__(16) u16 As[8192];    // [128][64]
  __shared__ __align__(16) u16 Bs[16384];   // [256][64]
  const int t = threadIdx.x;
  const int l = t & 63, w = t >> 6;
  const int nbx = N >> 8;
  const int qd = (int)gridDim.x >> 3;
  const int id = blockIdx.x;
  const int swz = (id & 7) * qd + (id >> 3);  // XCD swizzle (grid % 8 == 0)
  const int by = swz / nbx, bx = swz - by * nbx;

  const int scol = ((t & 7) ^ ((t >> 3) & 7)) * 8;
  const u16* gA = A + (size_t)(by * 128 + (t >> 3)) * K + scol;
  const u16* gB = Bt + (size_t)(bx * 256 + (t >> 3)) * K + scol;
  const size_t r64K = (size_t)64 * K;
  const int dst = t * 8;

  const int wr = w >> 2, wc = w & 3;  // 2M x 4N; wave out 64x64
  const int arow = (wr * 64 + (l & 15)) * 64;
  const int brow = (wc * 64 + (l & 15)) * 64;
  const int ck0 = ((l >> 4) ^ (l & 7)) * 8;
  const int ck1 = ((4 + (l >> 4)) ^ (l & 7)) * 8;

  const f32x4 fz = {0.f, 0.f, 0.f, 0.f};
  f32x4 acc[4][4];
#pragma unroll
  for (int i = 0; i < 4; ++i)
#pragma unroll
    for (int j = 0; j < 4; ++j) acc[i][j] = fz;

  const int nk = K >> 6;
  for (int kk = 0; kk < nk; ++kk) {
    __syncthreads();
    glds16(gA, As + dst);
    glds16(gA + r64K, As + 4096 + dst);
    glds16(gB, Bs + dst);
    glds16(gB + r64K, Bs + 4096 + dst);
    glds16(gB + 2 * r64K, Bs + 8192 + dst);
    glds16(gB + 3 * r64K, Bs + 12288 + dst);
    gA += 64;
    gB += 64;
    __syncthreads();
#pragma unroll
    for (int ks = 0; ks < 2; ++ks) {
      const int ck = ks ? ck1 : ck0;
      bf16x8 af[4], bv[4];
#pragma unroll
      for (int i = 0; i < 4; ++i)
        af[i] = *reinterpret_cast<const bf16x8*>(&As[arow + i * 1024 + ck]);
#pragma unroll
      for (int j = 0; j < 4; ++j)
        bv[j] = *reinterpret_cast<const bf16x8*>(&Bs[brow + j * 1024 + ck]);
      __builtin_amdgcn_s_setprio(1);
#pragma unroll
      for (int i = 0; i < 4; ++i)
#pragma unroll
        for (int j = 0; j < 4; ++j) acc[i][j] = MFMA16(af[i], bv[j], acc[i][j]);
      __builtin_amdgcn_s_setprio(0);
    }
  }

  const int r0 = by * 128 + wr * 64 + ((l >> 4) << 2);
  const int c0 = bx * 256 + wc * 64 + (l & 15);
#pragma unroll
  for (int mi = 0; mi < 4; ++mi)
#pragma unroll
    for (int ni = 0; ni < 4; ++ni) {
      const int col = c0 + ni * 16;
      const size_t base = (size_t)(r0 + mi * 16) * N + col;
      if (EPI == 0) {
#pragma unroll
        for (int r = 0; r < 4; ++r) Cb[base + (size_t)r * N] = f2bf(acc[mi][ni][r]);
      } else {
        const float bb = bias[col];
#pragma unroll
        for (int r = 0; r < 4; ++r) {
          const float x = acc[mi][ni][r] + bb;
          const float gl = 0.5f * x * (1.0f + erff(x * 0.70710678118654752f));
          Cb[base + (size_t)r * N] = f2bf(gl);
        }
      }
    }
}

// ---------------- reduce: out += P0 + P1 + bias  (4096x1024 f32) ----------------
__global__ __launch_bounds__(256) void reduce_k(float* __restrict__ out,
                                                const u16* __restrict__ P0,
                                                const u16* __restrict__ P1,
                                                const float* __restrict__ bias) {
  const int q0 = blockIdx.x * 256 + threadIdx.x;
#pragma unroll
  for (int it = 0; it < 2; ++it) {
    const size_t q = ((size_t)q0 + (size_t)it * 524288) * 4;
    float4 o = *reinterpret_cast<float4*>(&out[q]);
    const ushort4 a = *reinterpret_cast<const ushort4*>(&P0[q]);
    const ushort4 b = *reinterpret_cast<const ushort4*>(&P1[q]);
    const float4 bb = *reinterpret_cast<const float4*>(&bias[q & 1023]);
    o.x += bf2f(a.x) + bf2f(b.x) + bb.x;
    o.y += bf2f(a.y) + bf2f(b.y) + bb.y;
    o.z += bf2f(a.z) + bf2f(b.z) + bb.z;
    o.w += bf2f(a.w) + bf2f(b.w) + bb.w;
    *reinterpret_cast<float4*>(&out[q]) = o;
  }
}

// ---------------- causal flash attention (LDS-staged K/V, 8 waves, 128-row qblk) ----
__global__ __launch_bounds__(512) void attn_k(const u16* __restrict__ QKV,
                                              const u16* __restrict__ Vt,
                                              u16* __restrict__ O) {
  __shared__ __align__(16) u16 Kbuf[2][4096];
  __shared__ __align__(16) u16 Vbuf[2][4096];
  __shared__ __align__(16) u16 Plds[8][16][68];
  const int t = threadIdx.x;
  const int l = t & 63, w = t >> 6;
  const int g = l >> 4, c = l & 15;
  const int pj = blockIdx.x, bh = blockIdx.y;
  const int b = bh >> 4, h = bh & 15;
  const u16* Kp = QKV + (size_t)b * 2048 * 3072 + 1024 + h * 64;
  const u16* Vp = Vt + (size_t)bh * 64 * 2048;
  const f32x4 fz = {0.f, 0.f, 0.f, 0.f};
  const int srow = t >> 3;
  const int scol = ((t & 7) ^ (srow & 7)) * 8;
  u16* kdst0 = &Kbuf[0][w * 512];
  u16* kdst1 = &Kbuf[1][w * 512];
  u16* vdst0 = &Vbuf[0][w * 512];
  u16* vdst1 = &Vbuf[1][w * 512];
  const int ca = (g ^ (c & 7)) * 8;
  const int cb = ((g + 4) ^ (c & 7)) * 8;

#pragma unroll 1
  for (int hf = 0; hf < 2; ++hf) {
    const int qblk = hf ? (15 - pj) : pj;
    const int nkt = 2 * qblk + 2;
    const int qrow0 = qblk * 128 + w * 16;
    const size_t qoff = (size_t)(b * 2048 + qrow0 + c) * 3072 + h * 64 + g * 8;
    const bf16x8 qf0 = *reinterpret_cast<const bf16x8*>(&QKV[qoff]);
    const bf16x8 qf1 = *reinterpret_cast<const bf16x8*>(&QKV[qoff + 32]);
    f32x4 o[4];
    float m[4], lsl[4];
#pragma unroll
    for (int f = 0; f < 4; ++f) o[f] = fz;
#pragma unroll
    for (int r = 0; r < 4; ++r) {
      m[r] = -__builtin_inff();
      lsl[r] = 0.f;
    }
    glds16(Kp + (size_t)srow * 3072 + scol, kdst0);
    glds16(Vp + (size_t)srow * 2048 + scol, vdst0);
    __syncthreads();
    int cur = 0;

#pragma unroll 1
    for (int kt = 0; kt < nkt; ++kt) {
      const int key0 = kt * 64;
      if (kt + 1 < nkt) {
        const int kn = key0 + 64;
        glds16(Kp + (size_t)(kn + srow) * 3072 + scol, cur ? kdst0 : kdst1);
        glds16(Vp + (size_t)srow * 2048 + kn + scol, cur ? vdst0 : vdst1);
      }
      if (key0 <= qrow0 + 15) {
        const u16* Kc = Kbuf[cur];
        const u16* Vc = Vbuf[cur];
        f32x4 s4[4];
        __builtin_amdgcn_s_setprio(1);
#pragma unroll
        for (int kq = 0; kq < 4; ++kq) {
          const int rb = (c + 16 * kq) * 64;
          const bf16x8 k0 = *reinterpret_cast<const bf16x8*>(&Kc[rb + ca]);
          const bf16x8 k1 = *reinterpret_cast<const bf16x8*>(&Kc[rb + cb]);
          s4[kq] = MFMA16(qf0, k0, fz);
          s4[kq] = MFMA16(qf1, k1, s4[kq]);
        }
        __builtin_amdgcn_s_setprio(0);
        bf16x8 vf[8];
#pragma unroll
        for (int f = 0; f < 4; ++f) {
          const int rb = (c + 16 * f) * 64;
          vf[f * 2] = *reinterpret_cast<const bf16x8*>(&Vc[rb + ca]);
          vf[f * 2 + 1] = *reinterpret_cast<const bf16x8*>(&Vc[rb + cb]);
        }
        const bool maskT = (kt >= nkt - 2);
        float xs[4][4];
        float mx4 = -__builtin_inff();
#pragma unroll
        for (int r = 0; r < 4; ++r) {
          const int qg = qrow0 + g * 4 + r;
          xs[r][0] = s4[0][r] * 0.125f;
          xs[r][1] = s4[1][r] * 0.125f;
          xs[r][2] = s4[2][r] * 0.125f;
          xs[r][3] = s4[3][r] * 0.125f;
          if (maskT) {
            if (key0 + c > qg) xs[r][0] = -__builtin_inff();
            if (key0 + 16 + c > qg) xs[r][1] = -__builtin_inff();
            if (key0 + 32 + c > qg) xs[r][2] = -__builtin_inff();
            if (key0 + 48 + c > qg) xs[r][3] = -__builtin_inff();
          }
          const float a0 = fmaxf(xs[r][0], xs[r][1]);
          const float a1 = fmaxf(xs[r][2], xs[r][3]);
          mx4 = fmaxf(mx4, fmaxf(a0, a1) - m[r]);
        }
        if (!__all(mx4 <= 8.0f)) {
#pragma unroll
          for (int r = 0; r < 4; ++r) {
            float tm = fmaxf(fmaxf(xs[r][0], xs[r][1]), fmaxf(xs[r][2], xs[r][3]));
            tm = fmaxf(tm, __shfl_xor(tm, 1, 16));
            tm = fmaxf(tm, __shfl_xor(tm, 2, 16));
            tm = fmaxf(tm, __shfl_xor(tm, 4, 16));
            tm = fmaxf(tm, __shfl_xor(tm, 8, 16));
            const float mn = fmaxf(m[r], tm);
            const float scl = __expf(m[r] - mn);
            lsl[r] *= scl;
            m[r] = mn;
            o[0][r] *= scl;
            o[1][r] *= scl;
            o[2][r] *= scl;
            o[3][r] *= scl;
          }
        }
#pragma unroll
        for (int r = 0; r < 4; ++r) {
          const float p0 = __expf(xs[r][0] - m[r]), p1 = __expf(xs[r][1] - m[r]);
          const float p2 = __expf(xs[r][2] - m[r]), p3 = __expf(xs[r][3] - m[r]);
          lsl[r] += (p0 + p1) + (p2 + p3);
          const int pr = g * 4 + r;
          Plds[w][pr][c] = f2bf(p0);
          Plds[w][pr][c + 16] = f2bf(p1);
          Plds[w][pr][c + 32] = f2bf(p2);
          Plds[w][pr][c + 48] = f2bf(p3);
        }
        asm volatile("" ::: "memory");
        const bf16x8 pa0 = *reinterpret_cast<const bf16x8*>(&Plds[w][c][g * 8]);
        const bf16x8 pa1 = *reinterpret_cast<const bf16x8*>(&Plds[w][c][32 + g * 8]);
        __builtin_amdgcn_s_setprio(1);
#pragma unroll
        for (int f = 0; f < 4; ++f) {
          o[f] = MFMA16(pa0, vf[f * 2], o[f]);
          o[f] = MFMA16(pa1, vf[f * 2 + 1], o[f]);
        }
        __builtin_amdgcn_s_setprio(0);
      }
      __syncthreads();
      cur ^= 1;
    }

    u16* op = O + (size_t)(b * 2048 + qrow0 + g * 4) * 1024 + h * 64 + c;
#pragma unroll
    for (int r = 0; r < 4; ++r) {
      float ls = lsl[r];
      ls += __shfl_xor(ls, 1, 16);
      ls += __shfl_xor(ls, 2, 16);
      ls += __shfl_xor(ls, 4, 16);
      ls += __shfl_xor(ls, 8, 16);
      const float inv = 1.0f / ls;
#pragma unroll
      for (int f = 0; f < 4; ++f) op[(size_t)r * 1024 + f * 16] = f2bf(o[f][r] * inv);
    }
  }
}

// ---------------- launcher ----------------
extern "C" void kernel_launch(void* const* d_in, const int* in_sizes, int n_in,
                              void* d_out, int out_size, void* d_ws, size_t ws_size,
                              hipStream_t stream) {
  const float* H   = (const float*)d_in[0];
  const float* Wq  = (const float*)d_in[1];
  const float* Wk  = (const float*)d_in[2];
  const float* Wv  = (const float*)d_in[3];
  const float* Wo  = (const float*)d_in[4];
  const float* g1  = (const float*)d_in[5];
  const float* be1 = (const float*)d_in[6];
  const float* g2  = (const float*)d_in[7];
  const float* be2 = (const float*)d_in[8];
  const float* W1  = (const float*)d_in[9];
  const float* bb1 = (const float*)d_in[10];
  const float* W2  = (const float*)d_in[11];
  const float* bb2 = (const float*)d_in[12];
  float* out = (float*)d_out;

  if (ws_size < (size_t)67108864) return;  // need 64 MiB
  char* ws = (char*)d_ws;
  u16* Wqkvt  = (u16*)(ws + 0);         //  6.29MB  dead after QKV gemm
  u16* Xattn  = (u16*)(ws + 6291456);   //  8.39MB  ln1 out -> attn out -> proj input
  u16* QKV    = (u16*)(ws + 14680064);  // 25.17MB  dead after attn
  u16* Vt     = (u16*)(ws + 39845888);  //  8.39MB  dead after attn; later Xln2
  u16* Wot    = (u16*)(ws + 48234496);  //  2.10MB  live until proj done
  u16* W1t    = (u16*)(ws + 50331648);  //  8.39MB  live until MLP1 done
  u16* W2t    = (u16*)(ws + 58720256);  //  8.39MB  live until MLP2 done
  u16* Hmlp   = (u16*)(ws + 0);         // 33.55MB  overlay (after proj+lnres)
  u16* Xln2   = Vt;
  u16* PpProj = (u16*)(ws + 14680064);  // 16.78MB  proj partials (QKV region, dead;
                                        //          consumed by lnres before Hmlp)
  u16* Pp     = (u16*)(ws + 39845888);  // 16.78MB  MLP2 partials (Vt/Wot/W1t dead then)

  wconv12_k<<<dim3(32, 32, 12), dim3(32, 8), 0, stream>>>(Wq, Wk, Wv, Wo, W1, W2,
                                                          Wqkvt, Wot, W1t, W2t);
  ln_k<<<4096, 256, 0, stream>>>(H, g1, be1, Xattn);
  gemm_qkv<<<512, 512, 0, stream>>>(Xattn, Wqkvt, QKV, Vt, 4096, 3072, 1024);
  attn_k<<<dim3(8, 32), 512, 0, stream>>>(QKV, Vt, Xattn);
  gemm_bt64<0><<<512, 256, 0, stream>>>(Xattn, Wot, PpProj, nullptr, nullptr, nullptr,
                                        4096, 1024, 1024, 1);
  // fused: out = H + P0 + P1; Xln2 = LN(out)
  lnres_k<<<4096, 256, 0, stream>>>(out, H, PpProj, PpProj + (size_t)4096 * 1024,
                                    g2, be2, Xln2);
  gemm_wide<1><<<512, 512, 0, stream>>>(Xln2, W1t, Hmlp, bb1, 4096, 4096, 1024);
  gemm_bt64<0><<<512, 256, 0, stream>>>(Hmlp, W2t, Pp, nullptr, nullptr, nullptr,
                                        4096, 1024, 4096, 1);
  reduce_k<<<2048, 256, 0, stream>>>(out, Pp, Pp + (size_t)4096 * 1024, bb2);
}

// Round 25
// 220.807 us; speedup vs baseline: 1.1498x; 1.0013x over previous
//
#include <hip/hip_runtime.h>
#include <hip/hip_bf16.h>
#include <math.h>

typedef unsigned short u16;
typedef __bf16 bf16x8 __attribute__((ext_vector_type(8)));
typedef float f32x4 __attribute__((ext_vector_type(4)));
typedef u16 u16x8 __attribute__((ext_vector_type(8)));

#define MFMA16(a, b, c) __builtin_amdgcn_mfma_f32_16x16x32_bf16((a), (b), (c), 0, 0, 0)

__device__ __forceinline__ u16 f2bf(float f) {
  unsigned u = __float_as_uint(f);
  u += 0x7fffu + ((u >> 16) & 1u);
  return (u16)(u >> 16);
}
__device__ __forceinline__ float bf2f(u16 u) {
  return __uint_as_float((unsigned)u << 16);
}

__device__ __forceinline__ void glds16(const u16* g, u16* l) {
  __builtin_amdgcn_global_load_lds((__attribute__((address_space(1))) const void*)g,
                                   (__attribute__((address_space(3))) void*)l, 16, 0, 0);
}

// ---- fused head stage: z<12 = weight convert+transpose slices; z>=12 = LN1 rows ----
__global__ __launch_bounds__(256) void prep_k(const float* __restrict__ Wq,
                                              const float* __restrict__ Wk,
                                              const float* __restrict__ Wv,
                                              const float* __restrict__ Wo,
                                              const float* __restrict__ W1,
                                              const float* __restrict__ W2,
                                              u16* __restrict__ Wqkvt,
                                              u16* __restrict__ Wot,
                                              u16* __restrict__ W1t,
                                              u16* __restrict__ W2t,
                                              const float* __restrict__ H,
                                              const float* __restrict__ G1,
                                              const float* __restrict__ B1,
                                              u16* __restrict__ Xattn) {
  const int z = blockIdx.z;
  if (z < 12) {
    __shared__ u16 tile[32][33];
    const float* W;
    u16* Wt;
    int K, N, n0, k0;
    if (z < 4) {
      W = (z == 0) ? Wq : (z == 1) ? Wk : (z == 2) ? Wv : Wo;
      Wt = (z == 3) ? Wot : (Wqkvt + (size_t)z * 1024 * 1024);
      K = 1024; N = 1024;
      n0 = blockIdx.x * 32; k0 = blockIdx.y * 32;
    } else if (z < 8) {
      W = W1; Wt = W1t; K = 1024; N = 4096;
      n0 = blockIdx.x * 32 + (z - 4) * 1024; k0 = blockIdx.y * 32;
    } else {
      W = W2; Wt = W2t; K = 4096; N = 1024;
      n0 = blockIdx.x * 32; k0 = blockIdx.y * 32 + (z - 8) * 1024;
    }
    const int x = threadIdx.x, y = threadIdx.y;
#pragma unroll
    for (int i = 0; i < 4; ++i)
      tile[y + i * 8][x] = f2bf(W[(size_t)(k0 + y + i * 8) * N + n0 + x]);
    __syncthreads();
#pragma unroll
    for (int i = 0; i < 4; ++i)
      Wt[(size_t)(n0 + y + i * 8) * K + k0 + x] = tile[x][y + i * 8];
  } else {
    const int row = (z - 12) * 1024 + blockIdx.y * 32 + blockIdx.x;
    const int t = threadIdx.y * 32 + threadIdx.x;
    const float4 v = reinterpret_cast<const float4*>(H + (size_t)row * 1024)[t];
    float s = v.x + v.y + v.z + v.w;
    float q = v.x * v.x + v.y * v.y + v.z * v.z + v.w * v.w;
    for (int off = 32; off > 0; off >>= 1) {
      s += __shfl_down(s, off);
      q += __shfl_down(q, off);
    }
    __shared__ float ss[4], qs[4];
    const int w = t >> 6, l = t & 63;
    if (l == 0) { ss[w] = s; qs[w] = q; }
    __syncthreads();
    s = ss[0] + ss[1] + ss[2] + ss[3];
    q = qs[0] + qs[1] + qs[2] + qs[3];
    const float mu = s * (1.0f / 1024.0f);
    const float rs = rsqrtf(q * (1.0f / 1024.0f) - mu * mu + 1e-5f);
    const float4 gv = reinterpret_cast<const float4*>(G1)[t];
    const float4 bv = reinterpret_cast<const float4*>(B1)[t];
    union { u16 u[4]; unsigned long long ll; } pk;
    pk.u[0] = f2bf((v.x - mu) * rs * gv.x + bv.x);
    pk.u[1] = f2bf((v.y - mu) * rs * gv.y + bv.y);
    pk.u[2] = f2bf((v.z - mu) * rs * gv.z + bv.z);
    pk.u[3] = f2bf((v.w - mu) * rs * gv.w + bv.w);
    *reinterpret_cast<unsigned long long*>(Xattn + (size_t)row * 1024 + t * 4) = pk.ll;
  }
}

// ---- fused proj-split merge + LayerNorm: out = H+P0+P1 (fp32); Xln2 = LN(out) ----
__global__ __launch_bounds__(256) void lnres_k(float* __restrict__ out,
                                               const float* __restrict__ H,
                                               const u16* __restrict__ P0,
                                               const u16* __restrict__ P1,
                                               const float* __restrict__ G,
                                               const float* __restrict__ Bv,
                                               u16* __restrict__ xout) {
  const int row = blockIdx.x;
  const int t = threadIdx.x;
  const size_t q4 = (size_t)row * 256 + t;
  const float4 hv = reinterpret_cast<const float4*>(H)[q4];
  const ushort4 a = reinterpret_cast<const ushort4*>(P0)[q4];
  const ushort4 b = reinterpret_cast<const ushort4*>(P1)[q4];
  float4 v;
  v.x = hv.x + bf2f(a.x) + bf2f(b.x);
  v.y = hv.y + bf2f(a.y) + bf2f(b.y);
  v.z = hv.z + bf2f(a.z) + bf2f(b.z);
  v.w = hv.w + bf2f(a.w) + bf2f(b.w);
  reinterpret_cast<float4*>(out)[q4] = v;
  float s = v.x + v.y + v.z + v.w;
  float q = v.x * v.x + v.y * v.y + v.z * v.z + v.w * v.w;
  for (int off = 32; off > 0; off >>= 1) {
    s += __shfl_down(s, off);
    q += __shfl_down(q, off);
  }
  __shared__ float ss[4], qs[4];
  const int w = t >> 6, l = t & 63;
  if (l == 0) { ss[w] = s; qs[w] = q; }
  __syncthreads();
  s = ss[0] + ss[1] + ss[2] + ss[3];
  q = qs[0] + qs[1] + qs[2] + qs[3];
  const float mu = s * (1.0f / 1024.0f);
  const float rs = rsqrtf(q * (1.0f / 1024.0f) - mu * mu + 1e-5f);
  const float4 gv = reinterpret_cast<const float4*>(G)[t];
  const float4 bv = reinterpret_cast<const float4*>(Bv)[t];
  union { u16 u[4]; unsigned long long ll; } pk;
  pk.u[0] = f2bf((v.x - mu) * rs * gv.x + bv.x);
  pk.u[1] = f2bf((v.y - mu) * rs * gv.y + bv.y);
  pk.u[2] = f2bf((v.z - mu) * rs * gv.z + bv.z);
  pk.u[3] = f2bf((v.w - mu) * rs * gv.w + bv.w);
  *reinterpret_cast<unsigned long long*>(xout + (size_t)row * 1024 + t * 4) = pk.ll;
}

// ------- GEMM 128x128, BK=64 single-buffer (split-K core; kzSplit: 2 halves) --------
template <int EPI>
__global__ __launch_bounds__(256) void gemm_bt64(const u16* __restrict__ A,
                                                 const u16* __restrict__ Bt,
                                                 u16* __restrict__ Cb, float* Cf,
                                                 const float* __restrict__ bias,
                                                 const float* res, int M, int N,
                                                 int K, int kzSplit) {
  __shared__ __align__(16) u16 As[8192];   // [128][64]
  __shared__ __align__(16) u16 Bs[8192];
  const int t = threadIdx.x;
  const int l = t & 63, w = t >> 6;
  const int nbx = N >> 7;
  const int id = blockIdx.x;
  int tiles, tid, kz;
  if (kzSplit) {  // grid = 2 * tiles; kz = id >> 8 (tiles == 256)
    kz = id >> 8;
    tid = id & 255;
    tiles = 256;
  } else {
    kz = 0;
    tid = id;
    tiles = (int)gridDim.x;
  }
  const int qd = tiles >> 3;
  const int swz = (tid & 7) * qd + (tid >> 3);  // XCD swizzle (tiles % 8 == 0)
  const int by = swz / nbx, bx = swz - by * nbx;
  const int Keff = kzSplit ? (K >> 1) : K;
  const int koff = kz * Keff;

  const int scol = ((t & 7) ^ ((t >> 3) & 7)) * 8;
  const u16* gA = A + (size_t)(by * 128 + (t >> 3)) * K + koff + scol;
  const u16* gB = Bt + (size_t)(bx * 128 + (t >> 3)) * K + koff + scol;
  const size_t r32K = (size_t)32 * K;
  const int dst = t * 8;

  const int wr = w >> 1, wc = w & 1;
  const int arow = (wr * 64 + (l & 15)) * 64;
  const int brow = (wc * 64 + (l & 15)) * 64;
  const int ck0 = ((l >> 4) ^ (l & 7)) * 8;
  const int ck1 = ((4 + (l >> 4)) ^ (l & 7)) * 8;

  const f32x4 fz = {0.f, 0.f, 0.f, 0.f};
  f32x4 acc[4][4];
#pragma unroll
  for (int i = 0; i < 4; ++i)
#pragma unroll
    for (int j = 0; j < 4; ++j) acc[i][j] = fz;

  const int nk = Keff >> 6;
  for (int kk = 0; kk < nk; ++kk) {
    __syncthreads();
#pragma unroll
    for (int i = 0; i < 4; ++i) {
      glds16(gA + i * r32K, As + i * 2048 + dst);
      glds16(gB + i * r32K, Bs + i * 2048 + dst);
    }
    gA += 64;
    gB += 64;
    __syncthreads();
#pragma unroll
    for (int ks = 0; ks < 2; ++ks) {
      const int ck = ks ? ck1 : ck0;
      bf16x8 af[4], bv[4];
#pragma unroll
      for (int i = 0; i < 4; ++i)
        af[i] = *reinterpret_cast<const bf16x8*>(&As[arow + i * 1024 + ck]);
#pragma unroll
      for (int j = 0; j < 4; ++j)
        bv[j] = *reinterpret_cast<const bf16x8*>(&Bs[brow + j * 1024 + ck]);
      __builtin_amdgcn_s_setprio(1);
#pragma unroll
      for (int i = 0; i < 4; ++i)
#pragma unroll
        for (int j = 0; j < 4; ++j) acc[i][j] = MFMA16(af[i], bv[j], acc[i][j]);
      __builtin_amdgcn_s_setprio(0);
    }
  }

  const int r0 = by * 128 + wr * 64 + ((l >> 4) << 2);
  const int c0 = bx * 128 + wc * 64 + (l & 15);
  if (EPI == 0) {
    u16* Cp = Cb + (size_t)kz * M * N;
#pragma unroll
    for (int mi = 0; mi < 4; ++mi)
#pragma unroll
      for (int ni = 0; ni < 4; ++ni) {
        const size_t base = (size_t)(r0 + mi * 16) * N + (c0 + ni * 16);
#pragma unroll
        for (int r = 0; r < 4; ++r) Cp[base + (size_t)r * N] = f2bf(acc[mi][ni][r]);
      }
  } else {
#pragma unroll
    for (int mi = 0; mi < 4; ++mi)
#pragma unroll
      for (int ni = 0; ni < 4; ++ni) {
        const int col = c0 + ni * 16;
        const float bb = bias ? bias[col] : 0.0f;
        const size_t base = (size_t)(r0 + mi * 16) * N + col;
#pragma unroll
        for (int r = 0; r < 4; ++r) {
          const size_t idx = base + (size_t)r * N;
          Cf[idx] = res[idx] + acc[mi][ni][r] + bb;
        }
      }
  }
}

// ------- QKV GEMM 128x192, BK=64, 8 waves (2Mx4N, wave 64x48) ---------------------
__global__ __launch_bounds__(512) void gemm_qkv(const u16* __restrict__ A,
                                                const u16* __restrict__ Bt,
                                                u16* __restrict__ Cb,
                                                u16* __restrict__ Vt,
                                                int M, int N, int K) {
  __shared__ __align__(16) u16 As[8192];    // [128][64]
  __shared__ __align__(16) u16 Bs[12288];   // [192][64]
  const int t = threadIdx.x;
  const int l = t & 63, w = t >> 6;
  const int nbx = 16;  // N/192
  const int qd = (int)gridDim.x >> 3;
  const int id = blockIdx.x;
  const int swz = (id & 7) * qd + (id >> 3);  // XCD swizzle (grid % 8 == 0)
  const int by = swz / nbx, bx = swz - by * nbx;

  const int scol = ((t & 7) ^ ((t >> 3) & 7)) * 8;
  const u16* gA = A + (size_t)(by * 128 + (t >> 3)) * K + scol;
  const u16* gB = Bt + (size_t)(bx * 192 + (t >> 3)) * K + scol;
  const size_t r64K = (size_t)64 * K;
  const int dst = t * 8;

  const int wr = w >> 2, wc = w & 3;  // 2M x 4N; wave out 64x48
  const int arow = (wr * 64 + (l & 15)) * 64;
  const int brow = (wc * 48 + (l & 15)) * 64;
  const int ck0 = ((l >> 4) ^ (l & 7)) * 8;
  const int ck1 = ((4 + (l >> 4)) ^ (l & 7)) * 8;

  const f32x4 fz = {0.f, 0.f, 0.f, 0.f};
  f32x4 acc[4][3];
#pragma unroll
  for (int i = 0; i < 4; ++i)
#pragma unroll
    for (int j = 0; j < 3; ++j) acc[i][j] = fz;

  const int nk = K >> 6;
  for (int kk = 0; kk < nk; ++kk) {
    __syncthreads();
    glds16(gA, As + dst);
    glds16(gA + r64K, As + 4096 + dst);
    glds16(gB, Bs + dst);
    glds16(gB + r64K, Bs + 4096 + dst);
    glds16(gB + 2 * r64K, Bs + 8192 + dst);
    gA += 64;
    gB += 64;
    __syncthreads();
#pragma unroll
    for (int ks = 0; ks < 2; ++ks) {
      const int ck = ks ? ck1 : ck0;
      bf16x8 af[4], bv[3];
#pragma unroll
      for (int i = 0; i < 4; ++i)
        af[i] = *reinterpret_cast<const bf16x8*>(&As[arow + i * 1024 + ck]);
#pragma unroll
      for (int j = 0; j < 3; ++j)
        bv[j] = *reinterpret_cast<const bf16x8*>(&Bs[brow + j * 1024 + ck]);
      __builtin_amdgcn_s_setprio(1);
#pragma unroll
      for (int i = 0; i < 4; ++i)
#pragma unroll
        for (int j = 0; j < 3; ++j) acc[i][j] = MFMA16(af[i], bv[j], acc[i][j]);
      __builtin_amdgcn_s_setprio(0);
    }
  }

  const int r0 = by * 128 + wr * 64 + ((l >> 4) << 2);
  const int b = (by * 128) >> 11;  // 2048-row batch (tile never straddles)
#pragma unroll
  for (int mi = 0; mi < 4; ++mi) {
    const int row = r0 + mi * 16;
#pragma unroll
    for (int ni = 0; ni < 3; ++ni) {
      const int colblk = bx * 192 + wc * 48 + ni * 16;  // wave-uniform
      const int col = colblk + (l & 15);
      if (colblk >= 2048) {  // V fragment -> transposed Vt write
        const int h = (col - 2048) >> 6;
        const int dk = (col - 2048) & 63;
        const int tt = row - b * 2048;
        union { u16 u[4]; unsigned long long ll; } pk;
#pragma unroll
        for (int r = 0; r < 4; ++r) pk.u[r] = f2bf(acc[mi][ni][r]);
        *reinterpret_cast<unsigned long long*>(
            &Vt[(((size_t)b * 16 + h) * 64 + dk) * 2048 + tt]) = pk.ll;
      } else {
        const size_t base = (size_t)row * N + col;
#pragma unroll
        for (int r = 0; r < 4; ++r) Cb[base + (size_t)r * N] = f2bf(acc[mi][ni][r]);
      }
    }
  }
}

// ------- GEMM 128x256, BK=64 single-buffer, 8 waves (MLP1) --------------------------
template <int EPI>
__global__ __launch_bounds__(512) void gemm_wide(const u16* __restrict__ A,
                                                 const u16* __restrict__ Bt,
                                                 u16* __restrict__ Cb,
                                                 const float* __restrict__ bias,
                                                 int M, int N, int K) {
  __shared__ __align__(16) u16 As[8192];    // [128][64]
  __shared__ __align__(16) u16 Bs[16384];   // [256][64]
  const int t = threadIdx.x;
  const int l = t & 63, w = t >> 6;
  const int nbx = N >> 8;
  const int qd = (int)gridDim.x >> 3;
  const int id = blockIdx.x;
  const int swz = (id & 7) * qd + (id >> 3);  // XCD swizzle (grid % 8 == 0)
  const int by = swz / nbx, bx = swz - by * nbx;

  const int scol = ((t & 7) ^ ((t >> 3) & 7)) * 8;
  const u16* gA = A + (size_t)(by * 128 + (t >> 3)) * K + scol;
  const u16* gB = Bt + (size_t)(bx * 256 + (t >> 3)) * K + scol;
  const size_t r64K = (size_t)64 * K;
  const int dst = t * 8;

  const int wr = w >> 2, wc = w & 3;  // 2M x 4N; wave out 64x64
  const int arow = (wr * 64 + (l & 15)) * 64;
  const int brow = (wc * 64 + (l & 15)) * 64;
  const int ck0 = ((l >> 4) ^ (l & 7)) * 8;
  const int ck1 = ((4 + (l >> 4)) ^ (l & 7)) * 8;

  const f32x4 fz = {0.f, 0.f, 0.f, 0.f};
  f32x4 acc[4][4];
#pragma unroll
  for (int i = 0; i < 4; ++i)
#pragma unroll
    for (int j = 0; j < 4; ++j) acc[i][j] = fz;

  const int nk = K >> 6;
  for (int kk = 0; kk < nk; ++kk) {
    __syncthreads();
    glds16(gA, As + dst);
    glds16(gA + r64K, As + 4096 + dst);
    glds16(gB, Bs + dst);
    glds16(gB + r64K, Bs + 4096 + dst);
    glds16(gB + 2 * r64K, Bs + 8192 + dst);
    glds16(gB + 3 * r64K, Bs + 12288 + dst);
    gA += 64;
    gB += 64;
    __syncthreads();
#pragma unroll
    for (int ks = 0; ks < 2; ++ks) {
      const int ck = ks ? ck1 : ck0;
      bf16x8 af[4], bv[4];
#pragma unroll
      for (int i = 0; i < 4; ++i)
        af[i] = *reinterpret_cast<const bf16x8*>(&As[arow + i * 1024 + ck]);
#pragma unroll
      for (int j = 0; j < 4; ++j)
        bv[j] = *reinterpret_cast<const bf16x8*>(&Bs[brow + j * 1024 + ck]);
      __builtin_amdgcn_s_setprio(1);
#pragma unroll
      for (int i = 0; i < 4; ++i)
#pragma unroll
        for (int j = 0; j < 4; ++j) acc[i][j] = MFMA16(af[i], bv[j], acc[i][j]);
      __builtin_amdgcn_s_setprio(0);
    }
  }

  const int r0 = by * 128 + wr * 64 + ((l >> 4) << 2);
  const int c0 = bx * 256 + wc * 64 + (l & 15);
#pragma unroll
  for (int mi = 0; mi < 4; ++mi)
#pragma unroll
    for (int ni = 0; ni < 4; ++ni) {
      const int col = c0 + ni * 16;
      const size_t base = (size_t)(r0 + mi * 16) * N + col;
      if (EPI == 0) {
#pragma unroll
        for (int r = 0; r < 4; ++r) Cb[base + (size_t)r * N] = f2bf(acc[mi][ni][r]);
      } else {
        const float bb = bias[col];
#pragma unroll
        for (int r = 0; r < 4; ++r) {
          const float x = acc[mi][ni][r] + bb;
          const float gl = 0.5f * x * (1.0f + erff(x * 0.70710678118654752f));
          Cb[base + (size_t)r * N] = f2bf(gl);
        }
      }
    }
}

// ---------------- reduce: out += P0 + P1 + bias  (4096x1024 f32) ----------------
__global__ __launch_bounds__(256) void reduce_k(float* __restrict__ out,
                                                const u16* __restrict__ P0,
                                                const u16* __restrict__ P1,
                                                const float* __restrict__ bias) {
  const int q0 = blockIdx.x * 256 + threadIdx.x;
#pragma unroll
  for (int it = 0; it < 2; ++it) {
    const size_t q = ((size_t)q0 + (size_t)it * 524288) * 4;
    float4 o = *reinterpret_cast<float4*>(&out[q]);
    const ushort4 a = *reinterpret_cast<const ushort4*>(&P0[q]);
    const ushort4 b = *reinterpret_cast<const ushort4*>(&P1[q]);
    const float4 bb = *reinterpret_cast<const float4*>(&bias[q & 1023]);
    o.x += bf2f(a.x) + bf2f(b.x) + bb.x;
    o.y += bf2f(a.y) + bf2f(b.y) + bb.y;
    o.z += bf2f(a.z) + bf2f(b.z) + bb.z;
    o.w += bf2f(a.w) + bf2f(b.w) + bb.w;
    *reinterpret_cast<float4*>(&out[q]) = o;
  }
}

// ---------------- causal flash attention (LDS-staged K/V, 8 waves, 128-row qblk) ----
__global__ __launch_bounds__(512) void attn_k(const u16* __restrict__ QKV,
                                              const u16* __restrict__ Vt,
                                              u16* __restrict__ O) {
  __shared__ __align__(16) u16 Kbuf[2][4096];
  __shared__ __align__(16) u16 Vbuf[2][4096];
  __shared__ __align__(16) u16 Plds[8][16][68];
  const int t = threadIdx.x;
  const int l = t & 63, w = t >> 6;
  const int g = l >> 4, c = l & 15;
  const int pj = blockIdx.x, bh = blockIdx.y;
  const int b = bh >> 4, h = bh & 15;
  const u16* Kp = QKV + (size_t)b * 2048 * 3072 + 1024 + h * 64;
  const u16* Vp = Vt + (size_t)bh * 64 * 2048;
  const f32x4 fz = {0.f, 0.f, 0.f, 0.f};
  const int srow = t >> 3;
  const int scol = ((t & 7) ^ (srow & 7)) * 8;
  u16* kdst0 = &Kbuf[0][w * 512];
  u16* kdst1 = &Kbuf[1][w * 512];
  u16* vdst0 = &Vbuf[0][w * 512];
  u16* vdst1 = &Vbuf[1][w * 512];
  const int ca = (g ^ (c & 7)) * 8;
  const int cb = ((g + 4) ^ (c & 7)) * 8;

#pragma unroll 1
  for (int hf = 0; hf < 2; ++hf) {
    const int qblk = hf ? (15 - pj) : pj;
    const int nkt = 2 * qblk + 2;
    const int qrow0 = qblk * 128 + w * 16;
    const size_t qoff = (size_t)(b * 2048 + qrow0 + c) * 3072 + h * 64 + g * 8;
    const bf16x8 qf0 = *reinterpret_cast<const bf16x8*>(&QKV[qoff]);
    const bf16x8 qf1 = *reinterpret_cast<const bf16x8*>(&QKV[qoff + 32]);
    f32x4 o[4];
    float m[4], lsl[4];
#pragma unroll
    for (int f = 0; f < 4; ++f) o[f] = fz;
#pragma unroll
    for (int r = 0; r < 4; ++r) {
      m[r] = -__builtin_inff();
      lsl[r] = 0.f;
    }
    glds16(Kp + (size_t)srow * 3072 + scol, kdst0);
    glds16(Vp + (size_t)srow * 2048 + scol, vdst0);
    __syncthreads();
    int cur = 0;

#pragma unroll 1
    for (int kt = 0; kt < nkt; ++kt) {
      const int key0 = kt * 64;
      if (kt + 1 < nkt) {
        const int kn = key0 + 64;
        glds16(Kp + (size_t)(kn + srow) * 3072 + scol, cur ? kdst0 : kdst1);
        glds16(Vp + (size_t)srow * 2048 + kn + scol, cur ? vdst0 : vdst1);
      }
      if (key0 <= qrow0 + 15) {
        const u16* Kc = Kbuf[cur];
        const u16* Vc = Vbuf[cur];
        f32x4 s4[4];
        __builtin_amdgcn_s_setprio(1);
#pragma unroll
        for (int kq = 0; kq < 4; ++kq) {
          const int rb = (c + 16 * kq) * 64;
          const bf16x8 k0 = *reinterpret_cast<const bf16x8*>(&Kc[rb + ca]);
          const bf16x8 k1 = *reinterpret_cast<const bf16x8*>(&Kc[rb + cb]);
          s4[kq] = MFMA16(qf0, k0, fz);
          s4[kq] = MFMA16(qf1, k1, s4[kq]);
        }
        __builtin_amdgcn_s_setprio(0);
        bf16x8 vf[8];
#pragma unroll
        for (int f = 0; f < 4; ++f) {
          const int rb = (c + 16 * f) * 64;
          vf[f * 2] = *reinterpret_cast<const bf16x8*>(&Vc[rb + ca]);
          vf[f * 2 + 1] = *reinterpret_cast<const bf16x8*>(&Vc[rb + cb]);
        }
        const bool maskT = (kt >= nkt - 2);
        float xs[4][4];
        float mx4 = -__builtin_inff();
#pragma unroll
        for (int r = 0; r < 4; ++r) {
          const int qg = qrow0 + g * 4 + r;
          xs[r][0] = s4[0][r] * 0.125f;
          xs[r][1] = s4[1][r] * 0.125f;
          xs[r][2] = s4[2][r] * 0.125f;
          xs[r][3] = s4[3][r] * 0.125f;
          if (maskT) {
            if (key0 + c > qg) xs[r][0] = -__builtin_inff();
            if (key0 + 16 + c > qg) xs[r][1] = -__builtin_inff();
            if (key0 + 32 + c > qg) xs[r][2] = -__builtin_inff();
            if (key0 + 48 + c > qg) xs[r][3] = -__builtin_inff();
          }
          const float a0 = fmaxf(xs[r][0], xs[r][1]);
          const float a1 = fmaxf(xs[r][2], xs[r][3]);
          mx4 = fmaxf(mx4, fmaxf(a0, a1) - m[r]);
        }
        if (!__all(mx4 <= 8.0f)) {
#pragma unroll
          for (int r = 0; r < 4; ++r) {
            float tm = fmaxf(fmaxf(xs[r][0], xs[r][1]), fmaxf(xs[r][2], xs[r][3]));
            tm = fmaxf(tm, __shfl_xor(tm, 1, 16));
            tm = fmaxf(tm, __shfl_xor(tm, 2, 16));
            tm = fmaxf(tm, __shfl_xor(tm, 4, 16));
            tm = fmaxf(tm, __shfl_xor(tm, 8, 16));
            const float mn = fmaxf(m[r], tm);
            const float scl = __expf(m[r] - mn);
            lsl[r] *= scl;
            m[r] = mn;
            o[0][r] *= scl;
            o[1][r] *= scl;
            o[2][r] *= scl;
            o[3][r] *= scl;
          }
        }
#pragma unroll
        for (int r = 0; r < 4; ++r) {
          const float p0 = __expf(xs[r][0] - m[r]), p1 = __expf(xs[r][1] - m[r]);
          const float p2 = __expf(xs[r][2] - m[r]), p3 = __expf(xs[r][3] - m[r]);
          lsl[r] += (p0 + p1) + (p2 + p3);
          const int pr = g * 4 + r;
          Plds[w][pr][c] = f2bf(p0);
          Plds[w][pr][c + 16] = f2bf(p1);
          Plds[w][pr][c + 32] = f2bf(p2);
          Plds[w][pr][c + 48] = f2bf(p3);
        }
        asm volatile("" ::: "memory");
        const bf16x8 pa0 = *reinterpret_cast<const bf16x8*>(&Plds[w][c][g * 8]);
        const bf16x8 pa1 = *reinterpret_cast<const bf16x8*>(&Plds[w][c][32 + g * 8]);
        __builtin_amdgcn_s_setprio(1);
#pragma unroll
        for (int f = 0; f < 4; ++f) {
          o[f] = MFMA16(pa0, vf[f * 2], o[f]);
          o[f] = MFMA16(pa1, vf[f * 2 + 1], o[f]);
        }
        __builtin_amdgcn_s_setprio(0);
      }
      __syncthreads();
      cur ^= 1;
    }

    u16* op = O + (size_t)(b * 2048 + qrow0 + g * 4) * 1024 + h * 64 + c;
#pragma unroll
    for (int r = 0; r < 4; ++r) {
      float ls = lsl[r];
      ls += __shfl_xor(ls, 1, 16);
      ls += __shfl_xor(ls, 2, 16);
      ls += __shfl_xor(ls, 4, 16);
      ls += __shfl_xor(ls, 8, 16);
      const float inv = 1.0f / ls;
#pragma unroll
      for (int f = 0; f < 4; ++f) op[(size_t)r * 1024 + f * 16] = f2bf(o[f][r] * inv);
    }
  }
}

// ---------------- launcher ----------------
extern "C" void kernel_launch(void* const* d_in, const int* in_sizes, int n_in,
                              void* d_out, int out_size, void* d_ws, size_t ws_size,
                              hipStream_t stream) {
  const float* H   = (const float*)d_in[0];
  const float* Wq  = (const float*)d_in[1];
  const float* Wk  = (const float*)d_in[2];
  const float* Wv  = (const float*)d_in[3];
  const float* Wo  = (const float*)d_in[4];
  const float* g1  = (const float*)d_in[5];
  const float* be1 = (const float*)d_in[6];
  const float* g2  = (const float*)d_in[7];
  const float* be2 = (const float*)d_in[8];
  const float* W1  = (const float*)d_in[9];
  const float* bb1 = (const float*)d_in[10];
  const float* W2  = (const float*)d_in[11];
  const float* bb2 = (const float*)d_in[12];
  float* out = (float*)d_out;

  if (ws_size < (size_t)67108864) return;  // need 64 MiB
  char* ws = (char*)d_ws;
  u16* Wqkvt  = (u16*)(ws + 0);         //  6.29MB  dead after QKV gemm
  u16* Xattn  = (u16*)(ws + 6291456);   //  8.39MB  ln1 out -> attn out -> proj input
  u16* QKV    = (u16*)(ws + 14680064);  // 25.17MB  dead after attn
  u16* Vt     = (u16*)(ws + 39845888);  //  8.39MB  dead after attn; later Xln2
  u16* Wot    = (u16*)(ws + 48234496);  //  2.10MB  live until proj done
  u16* W1t    = (u16*)(ws + 50331648);  //  8.39MB  live until MLP1 done
  u16* W2t    = (u16*)(ws + 58720256);  //  8.39MB  live until MLP2 done
  u16* Hmlp   = (u16*)(ws + 0);         // 33.55MB  overlay (after proj+lnres)
  u16* Xln2   = Vt;
  u16* PpProj = (u16*)(ws + 14680064);  // 16.78MB  proj partials (QKV region, dead;
                                        //          consumed by lnres before Hmlp)
  u16* Pp     = (u16*)(ws + 39845888);  // 16.78MB  MLP2 partials (Vt/Wot/W1t dead then)

  prep_k<<<dim3(32, 32, 16), dim3(32, 8), 0, stream>>>(Wq, Wk, Wv, Wo, W1, W2,
                                                       Wqkvt, Wot, W1t, W2t,
                                                       H, g1, be1, Xattn);
  gemm_qkv<<<512, 512, 0, stream>>>(Xattn, Wqkvt, QKV, Vt, 4096, 3072, 1024);
  attn_k<<<dim3(8, 32), 512, 0, stream>>>(QKV, Vt, Xattn);
  gemm_bt64<0><<<512, 256, 0, stream>>>(Xattn, Wot, PpProj, nullptr, nullptr, nullptr,
                                        4096, 1024, 1024, 1);
  lnres_k<<<4096, 256, 0, stream>>>(out, H, PpProj, PpProj + (size_t)4096 * 1024,
                                    g2, be2, Xln2);
  gemm_wide<1><<<512, 512, 0, stream>>>(Xln2, W1t, Hmlp, bb1, 4096, 4096, 1024);
  gemm_bt64<0><<<512, 256, 0, stream>>>(Hmlp, W2t, Pp, nullptr, nullptr, nullptr,
                                        4096, 1024, 4096, 1);
  reduce_k<<<2048, 256, 0, stream>>>(out, Pp, Pp + (size_t)4096 * 1024, bb2);
}